// Round 12
// baseline (311.781 us; speedup 1.0000x reference)
//
#include <hip/hip_runtime.h>

typedef _Float16 f16x8 __attribute__((ext_vector_type(8)));
typedef _Float16 f16x4 __attribute__((ext_vector_type(4)));
typedef float    f32x4 __attribute__((ext_vector_type(4)));

// exact-erf GELU via Abramowitz-Stegun 7.1.26 (|erf err| <= 1.5e-7), ~14 VALU ops
__device__ __forceinline__ float gelu_f(float x) {
    float z  = 0.70710678118654752440f * x;
    float az = fabsf(z);
    float t  = 1.0f / fmaf(0.3275911f, az, 1.0f);
    float e  = __expf(-az * az);
    float p  = t * fmaf(t, fmaf(t, fmaf(t, fmaf(t, 1.061405429f, -1.453152027f),
                                        1.421413741f), -0.284496736f), 0.254829592f);
    float er = fmaf(-p, e, 1.0f);          // erf(|z|)
    float s  = (z < 0.0f) ? -er : er;      // erf(z), odd
    return 0.5f * x * (1.0f + s);
}

// async global->LDS, 16B per lane (dest = wave-uniform base + lane*16)
__device__ __forceinline__ void gload16(const void* g, void* l) {
    __builtin_amdgcn_global_load_lds(
        (const __attribute__((address_space(1))) unsigned int*)g,
        (__attribute__((address_space(3))) unsigned int*)l, 16, 0, 0);
}

// ---------------------------------------------------------------- K1: conv+gelu
__global__ void conv_kernel(const float* __restrict__ xs, const float* __restrict__ dww,
                            const float* __restrict__ dwb, _Float16* __restrict__ Gt)
{
    int b = blockIdx.x, t = blockIdx.y, n = threadIdx.x;
    float g = 0.f;
    if (t < 97) {
        float y = 0.f;
        #pragma unroll
        for (int j = 0; j < 12; ++j) {
            int tt = t + j - 6;
            if (tt >= 0 && tt < 96)
                y += dww[n*12 + j] * xs[((size_t)b*96 + tt)*256 + n];
        }
        g = gelu_f(y + dwb[n]);
    }
    Gt[((size_t)b*128 + t)*256 + n] = (_Float16)g;
}

// ---------------------------------------------------------------- K-cvt (merged: pw_w cvt | small-w cvt | zero accum)
__global__ void cvt_pw_kernel(const float* __restrict__ src, _Float16* __restrict__ dst,
                              const float* __restrict__ ipw, const float* __restrict__ opw,
                              const float* __restrict__ pjw, _Float16* __restrict__ wAll,
                              float* __restrict__ zp)
{
    int bid = blockIdx.x, tid = threadIdx.x;
    if (bid < 8192) {
        size_t i = ((size_t)bid*256 + tid) * 4;
        float4 v = *(const float4*)&src[i];
        f16x4 o; o[0] = (_Float16)v.x; o[1] = (_Float16)v.y; o[2] = (_Float16)v.z; o[3] = (_Float16)v.w;
        *(f16x4*)&dst[i] = o;
    } else if (bid < 8512) {
        int i = (bid - 8192)*256 + tid;  // < 81920
        float v = (i < 49152) ? ipw[i] : (i < 65536 ? opw[i - 49152] : pjw[i - 65536]);
        wAll[i] = (_Float16)v;
    } else {
        int i = (bid - 8512)*256 + tid;  // zero 20348 floats = 5087 float4
        if (i < 5087) {
            float4 z = {0.f, 0.f, 0.f, 0.f};
            *(float4*)&zp[i*4] = z;
        }
    }
}

// ---------------------------------------------------------------- K2: pointwise GEMM + gelu + mean
// v4: NO LDS, NO barriers. Both tiles are L2-resident (A 64KB reused by 16
// consecutive blocks; B 1MB shared chip-wide) -> fragments load straight from
// global; compiler software-pipelines freely. unroll 2 caps in-flight regs.
// Operand-swapped MFMA: D-rows = t (regs), D-cols = o (lanes). In-register t-sum.
__global__ __launch_bounds__(256) void pw_kernel(const _Float16* __restrict__ W,
                                                 const _Float16* __restrict__ Gt,
                                                 const float* __restrict__ pwb,
                                                 float* __restrict__ xmean)
{
    __shared__ float red[128][2];

    int x = blockIdx.x;
    int xcd = x & 7, ii = x >> 3;
    int ob = xcd * 32 + (ii >> 4);   // o-block: slow
    int b  = ii & 15;                // batch: fast (A-tile L2 reuse)
    const _Float16* Arow = W  + (size_t)ob * 128 * 256;
    const _Float16* Brow = Gt + (size_t)b  * 128 * 256;

    int tid = threadIdx.x, w = tid >> 6, l = tid & 63, lr = l & 15, lk = l >> 4;
    int wr = w >> 1, wc = w & 1;

    const _Float16* Ap = Arow + (size_t)(wr*64 + lr)*256 + lk*8;  // + i*4096 + ks*32
    const _Float16* Bp = Brow + (size_t)(wc*64 + lr)*256 + lk*8;  // + j*4096 + ks*32

    f32x4 acc[4][4];
    #pragma unroll
    for (int i = 0; i < 4; ++i)
        #pragma unroll
        for (int j = 0; j < 4; ++j)
            acc[i][j] = f32x4{0.f, 0.f, 0.f, 0.f};

    #pragma unroll 2
    for (int ks = 0; ks < 8; ++ks) {
        int k0 = ks * 32;
        f16x8 a[4], bb[4];
        #pragma unroll
        for (int i = 0; i < 4; ++i)
            a[i] = *(const f16x8*)&Ap[i*4096 + k0];
        #pragma unroll
        for (int j = 0; j < 4; ++j)
            if (wc == 0 || j < 3)            // wc=1, j=3 -> t=112..127 all padding
                bb[j] = *(const f16x8*)&Bp[j*4096 + k0];
        #pragma unroll
        for (int i = 0; i < 4; ++i)
            #pragma unroll
            for (int j = 0; j < 4; ++j)
                if (wc == 0 || j < 3)
                    acc[i][j] = __builtin_amdgcn_mfma_f32_16x16x32_f16(bb[j], a[i], acc[i][j], 0, 0, 0);
    }

    // epilogue: per lane o = wr*64+i*16+lr; t-values live in (j, lk, r)
    #pragma unroll
    for (int i = 0; i < 4; ++i) {
        int og = ob*128 + wr*64 + i*16 + lr;
        float pbv = pwb[og];
        float s = 0.f;
        if (wc == 0) {
            #pragma unroll
            for (int j = 0; j < 4; ++j)
                #pragma unroll
                for (int r = 0; r < 4; ++r)
                    s += gelu_f(acc[i][j][r] + pbv);      // t = j*16+lk*4+r <= 63, all live
        } else {
            #pragma unroll
            for (int j = 0; j < 2; ++j)
                #pragma unroll
                for (int r = 0; r < 4; ++r)
                    s += gelu_f(acc[i][j][r] + pbv);      // t = 64..95, all live
            if (lk == 0) s += gelu_f(acc[i][2][0] + pbv); // t = 96 only
        }
        s += __shfl_xor(s, 16, 64);
        s += __shfl_xor(s, 32, 64);
        if (lk == 0) red[wr*64 + i*16 + lr][wc] = s;
    }
    __syncthreads();
    if (tid < 128) {
        float v = (red[tid][0] + red[tid][1]) * (1.f / 97.f);
        xmean[(size_t)b*32768 + ob*128 + tid] = v;
    }
}

// ---------------------------------------------------------------- K3: layernorm (+q out, q hi/lo f16, ||q||^2)
__global__ void ln_kernel(const float* __restrict__ xm, const float* __restrict__ g,
                          const float* __restrict__ bta, float* __restrict__ qout,
                          _Float16* __restrict__ qh, _Float16* __restrict__ qlo,
                          float* __restrict__ qss)
{
    int bn = blockIdx.x, lane = threadIdx.x;  // 64 threads
    float x0 = xm[(size_t)bn*128 + lane];
    float x1 = xm[(size_t)bn*128 + 64 + lane];
    float s = x0 + x1;
    #pragma unroll
    for (int m = 1; m < 64; m <<= 1) s += __shfl_xor(s, m, 64);
    float mu = s * (1.f/128.f);
    float d0 = x0 - mu, d1 = x1 - mu;
    float v = d0*d0 + d1*d1;
    #pragma unroll
    for (int m = 1; m < 64; m <<= 1) v += __shfl_xor(v, m, 64);
    float rs = 1.0f / sqrtf(v * (1.f/128.f) + 1e-5f);
    float q0 = d0*rs*g[lane]    + bta[lane];
    float q1 = d1*rs*g[64+lane] + bta[64+lane];
    qout[(size_t)bn*128 + lane]      = q0;
    qout[(size_t)bn*128 + 64 + lane] = q1;
    _Float16 h0 = (_Float16)q0, h1 = (_Float16)q1;
    qh[(size_t)bn*128 + lane]      = h0;
    qh[(size_t)bn*128 + 64 + lane] = h1;
    qlo[(size_t)bn*128 + lane]      = (_Float16)(q0 - (float)h0);
    qlo[(size_t)bn*128 + 64 + lane] = (_Float16)(q1 - (float)h1);
    float ss = q0*q0 + q1*q1;
    #pragma unroll
    for (int m = 1; m < 64; m <<= 1) ss += __shfl_xor(ss, m, 64);
    if (lane == 0) atomicAdd(&qss[bn >> 8], ss);
}

// ---------------------------------------------------------------- K4: similarity via MFMA, LDS-staged mem
// (unchanged from R11)
__global__ __launch_bounds__(256) void simgemm_kernel(const _Float16* __restrict__ qhi,
                                                      const _Float16* __restrict__ qlo,
                                                      const float* __restrict__ mem,
                                                      float* __restrict__ dotp,
                                                      float* __restrict__ mn2)
{
    __shared__ __align__(16) float Ms[2][16][256];   // 16KB per buf
    __shared__ f32x4 redls[4][64];
    __shared__ float redn[4][16];

    int tid = threadIdx.x, w = tid >> 6, l = tid & 63, lr = l & 15, lk = l >> 4;
    int m0 = blockIdx.y * 16;
    int kwin = blockIdx.x * 1024;
    int rowm = m0 + lr;

    auto stage = [&](int buf, int sw) {
        #pragma unroll
        for (int j = 0; j < 4; ++j) {
            int r = w*4 + j;                          // local row, wave-uniform
            int rowg = m0 + r; if (rowg > 1195) rowg = 1195;
            const float* src = mem + (size_t)rowg*32768 + kwin + sw*256 + (l ^ (r & 7))*4;
            gload16(src, &Ms[buf][r][0]);             // + lane*16B by HW
        }
    };

    f32x4 acc_a = {0.f,0.f,0.f,0.f}, acc_b = {0.f,0.f,0.f,0.f};
    float nacc = 0.f;

    stage(0, 0);
    __syncthreads();
    for (int sw = 0; sw < 4; ++sw) {
        int cur = sw & 1;
        if (sw < 3) stage(cur ^ 1, sw + 1);
        #pragma unroll
        for (int cc = 0; cc < 2; ++cc) {
            int kl = w*64 + cc*32;                    // k within sub-window
            int s0 = (kl + lk*8) >> 2;                // 16B slot 0..62
            float4 v0 = *(const float4*)&Ms[cur][lr][(s0       ^ (lr & 7))*4];
            float4 v1 = *(const float4*)&Ms[cur][lr][((s0 + 1) ^ (lr & 7))*4];
            int kg = kwin + sw*256 + kl + lk*8;
            f16x8 ah = *(const f16x8*)&qhi[(size_t)lr*32768 + kg];
            f16x8 al = *(const f16x8*)&qlo[(size_t)lr*32768 + kg];
            float e0 = v0.x, e1 = v0.y, e2 = v0.z, e3 = v0.w;
            float e4 = v1.x, e5 = v1.y, e6 = v1.z, e7 = v1.w;
            f16x8 bh;
            bh[0]=(_Float16)e0; bh[1]=(_Float16)e1; bh[2]=(_Float16)e2; bh[3]=(_Float16)e3;
            bh[4]=(_Float16)e4; bh[5]=(_Float16)e5; bh[6]=(_Float16)e6; bh[7]=(_Float16)e7;
            nacc = fmaf(e0,e0, fmaf(e1,e1, fmaf(e2,e2, fmaf(e3,e3, nacc))));
            nacc = fmaf(e4,e4, fmaf(e5,e5, fmaf(e6,e6, fmaf(e7,e7, nacc))));
            acc_a = __builtin_amdgcn_mfma_f32_16x16x32_f16(ah, bh, acc_a, 0, 0, 0);
            acc_b = __builtin_amdgcn_mfma_f32_16x16x32_f16(al, bh, acc_b, 0, 0, 0);
        }
        __syncthreads();
    }

    // mem row norms within wave (lanes lr,lr+16,lr+32,lr+48 share a row)
    nacc += __shfl_xor(nacc, 16, 64);
    nacc += __shfl_xor(nacc, 32, 64);

    // cross-wave reduction, one atomic set per block
    f32x4 tot = acc_a + acc_b;
    redls[w][l] = tot;
    if (lk == 0) redn[w][lr] = nacc;
    __syncthreads();
    if (w == 0) {
        tot = redls[0][l];
        tot += redls[1][l]; tot += redls[2][l]; tot += redls[3][l];
        if (rowm < 1196) {
            #pragma unroll
            for (int r = 0; r < 4; ++r)
                atomicAdd(&dotp[(lk*4 + r)*1196 + rowm], tot[r]);
            if (lk == 0)
                atomicAdd(&mn2[rowm], redn[0][lr] + redn[1][lr] + redn[2][lr] + redn[3][lr]);
        }
    }
}

// ---------------------------------------------------------------- K5: finalize sim + top-8
__global__ void topk_kernel(const float* __restrict__ dotp, const float* __restrict__ mn2,
                            const float* __restrict__ qss, const int* __restrict__ seaq,
                            const float* __restrict__ yq, const int* __restrict__ seam,
                            const float* __restrict__ ym, int* __restrict__ idx)
{
    __shared__ float sc[1216];
    int b = blockIdx.x, lane = threadIdx.x;  // 64 threads
    float qn = fmaxf(sqrtf(qss[b]), 1e-12f);
    int sq = seaq[b];
    float yqv = yq[b];
    for (int m = lane; m < 1216; m += 64) {
        float v = -3e38f;
        if (m < 1196) {
            float s = dotp[b*1196 + m] / (qn * fmaxf(sqrtf(mn2[m]), 1e-12f));
            if (seam[m] != sq) s = -10000.0f;
            float dy = fabsf(yqv - ym[m]);
            v = s * (1.0f - 0.5f * expf(-0.5f * dy));
        }
        sc[m] = v;
    }
    __syncthreads();
    for (int kk = 0; kk < 8; ++kk) {
        float bv = -3e38f; int bi = 0x7fffffff;
        for (int m = lane; m < 1216; m += 64) {
            float v = sc[m];
            if (v > bv) { bv = v; bi = m; }
        }
        #pragma unroll
        for (int mk = 1; mk < 64; mk <<= 1) {
            float ov = __shfl_xor(bv, mk, 64);
            int   oi = __shfl_xor(bi, mk, 64);
            if (ov > bv || (ov == bv && oi < bi)) { bv = ov; bi = oi; }
        }
        if (lane == 0) { idx[b*8 + kk] = bi; sc[bi] = -3e38f; }
        __syncthreads();
    }
}

// ---------------------------------------------------------------- K6: gather retrieved rows -> f16
__global__ void gather_kernel(const float* __restrict__ mem, const int* __restrict__ idx,
                              _Float16* __restrict__ kvg)
{
    int bk = blockIdx.x;                       // b*8+k
    int row = idx[bk];
    size_t off = ((size_t)blockIdx.y*256 + threadIdx.x) * 4;
    float4 v = *(const float4*)&mem[(size_t)row*32768 + off];
    f16x4 o; o[0] = (_Float16)v.x; o[1] = (_Float16)v.y; o[2] = (_Float16)v.z; o[3] = (_Float16)v.w;
    *(f16x4*)&kvg[(size_t)bk*32768 + off] = o;
}

// ---------------------------------------------------------------- merged q/k/v projection (grid 64+512+512)
__global__ __launch_bounds__(256) void qkv_kernel(const _Float16* __restrict__ qh,
                                                  const _Float16* __restrict__ kvg,
                                                  const _Float16* __restrict__ wAll,
                                                  const float* __restrict__ ipb,
                                                  _Float16* __restrict__ qp,
                                                  _Float16* __restrict__ kp,
                                                  _Float16* __restrict__ vp)
{
    int bid = blockIdx.x;
    const _Float16* A; const _Float16* Wm; const float* bias; _Float16* Y; int blk;
    if (bid < 64)       { A = qh;  Wm = wAll;         bias = ipb;       Y = qp; blk = bid; }
    else if (bid < 576) { A = kvg; Wm = wAll + 16384; bias = ipb + 128; Y = kp; blk = bid - 64; }
    else                { A = kvg; Wm = wAll + 32768; bias = ipb + 256; Y = vp; blk = bid - 576; }

    int tid = threadIdx.x, w = tid >> 6, l = tid & 63, lr = l & 15, lk = l >> 4;
    int r0 = blk * 64 + w * 16;
    f32x4 acc[8];
    #pragma unroll
    for (int j = 0; j < 8; ++j) acc[j] = f32x4{0.f, 0.f, 0.f, 0.f};
    #pragma unroll
    for (int k0 = 0; k0 < 128; k0 += 32) {
        f16x8 a = *(const f16x8*)&A[(size_t)(r0 + lr)*128 + k0 + lk*8];
        #pragma unroll
        for (int j = 0; j < 8; ++j) {
            f16x8 bb = *(const f16x8*)&Wm[(j*16 + lr)*128 + k0 + lk*8];
            acc[j] = __builtin_amdgcn_mfma_f32_16x16x32_f16(a, bb, acc[j], 0, 0, 0);
        }
    }
    #pragma unroll
    for (int j = 0; j < 8; ++j) {
        #pragma unroll
        for (int r = 0; r < 4; ++r) {
            int row = r0 + lk*4 + r, col = j*16 + lr;
            Y[(size_t)row*128 + col] = (_Float16)(acc[j][r] + bias[col]);
        }
    }
}

// ---------------------------------------------------------------- generic (R x 128) @ W[128][128]^T + bias
template<int OUT_F32>
__global__ __launch_bounds__(256) void gemm128_kernel(const _Float16* __restrict__ A,
                                                      const _Float16* __restrict__ W,
                                                      const float* __restrict__ bias,
                                                      void* __restrict__ Y, int R)
{
    int tid = threadIdx.x, w = tid >> 6, l = tid & 63, lr = l & 15, lk = l >> 4;
    int r0 = blockIdx.x * 64 + w * 16;
    f32x4 acc[8];
    #pragma unroll
    for (int j = 0; j < 8; ++j) acc[j] = f32x4{0.f, 0.f, 0.f, 0.f};
    #pragma unroll
    for (int k0 = 0; k0 < 128; k0 += 32) {
        f16x8 a = *(const f16x8*)&A[(size_t)(r0 + lr)*128 + k0 + lk*8];
        #pragma unroll
        for (int j = 0; j < 8; ++j) {
            f16x8 bb = *(const f16x8*)&W[(j*16 + lr)*128 + k0 + lk*8];
            acc[j] = __builtin_amdgcn_mfma_f32_16x16x32_f16(a, bb, acc[j], 0, 0, 0);
        }
    }
    #pragma unroll
    for (int j = 0; j < 8; ++j) {
        #pragma unroll
        for (int r = 0; r < 4; ++r) {
            int row = r0 + lk*4 + r, col = j*16 + lr;
            float v = acc[j][r] + bias[col];
            if (OUT_F32) ((float*)Y)[(size_t)row*128 + col] = v;
            else         ((_Float16*)Y)[(size_t)row*128 + col] = (_Float16)v;
        }
    }
}

// ---------------------------------------------------------------- K8: 8-key attention
__global__ void attn_kernel(const _Float16* __restrict__ qp, const _Float16* __restrict__ kp,
                            const _Float16* __restrict__ vp, _Float16* __restrict__ ctx)
{
    int bn = blockIdx.x;                 // b*256+n
    int b = bn >> 8, n = bn & 255;
    int tid = threadIdx.x;               // 128, d = tid, h = tid>>5
    float qv = (float)qp[(size_t)bn*128 + tid];
    float sc[8];
    #pragma unroll
    for (int k = 0; k < 8; ++k) {
        float p = qv * (float)kp[(((size_t)(b*8 + k)*256 + n)*128) + tid];
        #pragma unroll
        for (int m = 1; m < 32; m <<= 1) p += __shfl_xor(p, m, 64);
        sc[k] = p * 0.17677669529663687f;   // 1/sqrt(32)
    }
    float mx = sc[0];
    #pragma unroll
    for (int k = 1; k < 8; ++k) mx = fmaxf(mx, sc[k]);
    float den = 0.f;
    #pragma unroll
    for (int k = 0; k < 8; ++k) { sc[k] = expf(sc[k] - mx); den += sc[k]; }
    float inv = 1.f / den;
    float c = 0.f;
    #pragma unroll
    for (int k = 0; k < 8; ++k)
        c += sc[k] * (float)vp[(((size_t)(b*8 + k)*256 + n)*128) + tid];
    ctx[(size_t)bn*128 + tid] = (_Float16)(c * inv);
}

// ================================================================ launch
extern "C" void kernel_launch(void* const* d_in, const int* in_sizes, int n_in,
                              void* d_out, int out_size, void* d_ws, size_t ws_size,
                              hipStream_t stream)
{
    const float* x_scalar = (const float*)d_in[0];
    const int*   season_q = (const int*)d_in[1];
    const float* year_q   = (const float*)d_in[2];
    const float* dw_w     = (const float*)d_in[3];
    const float* dw_b     = (const float*)d_in[4];
    const float* pw_w     = (const float*)d_in[5];
    const float* pw_b     = (const float*)d_in[6];
    const float* ln_g     = (const float*)d_in[7];
    const float* ln_b     = (const float*)d_in[8];
    const float* memb     = (const float*)d_in[9];
    const int*   mseas    = (const int*)d_in[10];
    const float* myear    = (const float*)d_in[11];
    const float* ipw      = (const float*)d_in[12];
    const float* ipb      = (const float*)d_in[13];
    const float* opw      = (const float*)d_in[14];
    const float* opb      = (const float*)d_in[15];
    const float* pjw      = (const float*)d_in[16];
    const float* pjb      = (const float*)d_in[17];

    char* wsb = (char*)d_ws;
    _Float16* Wf   = (_Float16*)(wsb + 0);            // 16,777,216
    _Float16* Gt   = (_Float16*)(wsb + 16777216);     //  1,048,576
    float*    xmean= (float*)   (wsb + 17825792);     //  2,097,152
    _Float16* qh   = (_Float16*)(wsb + 19922944);     //  1,048,576
    float*    qss  = (float*)   (wsb + 20971520);     //        64
    float*    dotp = (float*)   (wsb + 20971584);     //     76,544
    float*    mn2  = (float*)   (wsb + 21048128);     //      4,784
    int*      idxb = (int*)     (wsb + 21052928);     //        512
    _Float16* kvg  = (_Float16*)(wsb + 21053440);     //  8,388,608
    _Float16* qp   = (_Float16*)(wsb + 29442048);     //  1,048,576
    _Float16* kp   = (_Float16*)(wsb + 30490624);     //  8,388,608
    _Float16* vp   = (_Float16*)(wsb + 38879232);     //  8,388,608
    _Float16* ctx  = (_Float16*)(wsb + 47267840);     //  1,048,576
    _Float16* out1 = (_Float16*)(wsb + 48316416);     //  1,048,576
    _Float16* wAll = (_Float16*)(wsb + 49364992);     //    163,840  (wq|wk|wv|wo|wp)
    _Float16* qlo  = (_Float16*)(wsb + 49528832);     //  1,048,576

    float* outp = (float*)d_out;
    float* qout = (float*)d_out + 524288;

    // merged: pw_w->f16 | small weights->f16 | zero accumulators
    cvt_pw_kernel<<<8532, 256, 0, stream>>>(pw_w, Wf, ipw, opw, pjw, wAll,
                                            (float*)(wsb + 20971520));
    conv_kernel<<<dim3(16, 128), 256, 0, stream>>>(x_scalar, dw_w, dw_b, Gt);

    // big fused pointwise GEMM + gelu + mean (no-LDS, barrier-free K-loop)
    pw_kernel<<<4096, 256, 0, stream>>>(Wf, Gt, pw_b, xmean);

    // layernorm -> q (f32 to d_out, f16 hi/lo, ||q||^2)
    ln_kernel<<<4096, 64, 0, stream>>>(xmean, ln_g, ln_b, qout, qh, qlo, qss);

    // similarity via MFMA + norms, then masked/diversity top-8
    simgemm_kernel<<<dim3(32, 75), 256, 0, stream>>>(qh, qlo, memb, dotp, mn2);
    topk_kernel<<<16, 64, 0, stream>>>(dotp, mn2, qss, season_q, year_q, mseas, myear, idxb);

    // gather retrieved memories -> f16
    gather_kernel<<<dim3(128, 32), 256, 0, stream>>>(memb, idxb, kvg);

    // merged q/k/v projections
    qkv_kernel<<<1088, 256, 0, stream>>>(qh, kvg, wAll, ipb, qp, kp, vp);

    // attention
    attn_kernel<<<4096, 128, 0, stream>>>(qp, kp, vp, ctx);

    // output projections
    gemm128_kernel<0><<<64, 256, 0, stream>>>(ctx,  wAll + 49152, opb, (void*)out1, 4096);
    gemm128_kernel<1><<<64, 256, 0, stream>>>(out1, wAll + 65536, pjb, (void*)outp, 4096);
}

// Round 13
// 243.823 us; speedup vs baseline: 1.2787x; 1.2787x over previous
//
#include <hip/hip_runtime.h>

typedef _Float16 f16x8 __attribute__((ext_vector_type(8)));
typedef _Float16 f16x4 __attribute__((ext_vector_type(4)));
typedef float    f32x4 __attribute__((ext_vector_type(4)));

// exact-erf GELU via Abramowitz-Stegun 7.1.26 (|erf err| <= 1.5e-7), ~14 VALU ops
__device__ __forceinline__ float gelu_f(float x) {
    float z  = 0.70710678118654752440f * x;
    float az = fabsf(z);
    float t  = 1.0f / fmaf(0.3275911f, az, 1.0f);
    float e  = __expf(-az * az);
    float p  = t * fmaf(t, fmaf(t, fmaf(t, fmaf(t, 1.061405429f, -1.453152027f),
                                        1.421413741f), -0.284496736f), 0.254829592f);
    float er = fmaf(-p, e, 1.0f);          // erf(|z|)
    float s  = (z < 0.0f) ? -er : er;      // erf(z), odd
    return 0.5f * x * (1.0f + s);
}

// async global->LDS, 16B per lane (dest = wave-uniform base + lane*16)
__device__ __forceinline__ void gload16(const void* g, void* l) {
    __builtin_amdgcn_global_load_lds(
        (const __attribute__((address_space(1))) unsigned int*)g,
        (__attribute__((address_space(3))) unsigned int*)l, 16, 0, 0);
}

// ---------------------------------------------------------------- K1: conv+gelu
__global__ void conv_kernel(const float* __restrict__ xs, const float* __restrict__ dww,
                            const float* __restrict__ dwb, _Float16* __restrict__ Gt)
{
    int b = blockIdx.x, t = blockIdx.y, n = threadIdx.x;
    float g = 0.f;
    if (t < 97) {
        float y = 0.f;
        #pragma unroll
        for (int j = 0; j < 12; ++j) {
            int tt = t + j - 6;
            if (tt >= 0 && tt < 96)
                y += dww[n*12 + j] * xs[((size_t)b*96 + tt)*256 + n];
        }
        g = gelu_f(y + dwb[n]);
    }
    Gt[((size_t)b*128 + t)*256 + n] = (_Float16)g;
}

// ---------------------------------------------------------------- K-cvt (merged: pw_w cvt | small-w cvt | zero accum)
__global__ void cvt_pw_kernel(const float* __restrict__ src, _Float16* __restrict__ dst,
                              const float* __restrict__ ipw, const float* __restrict__ opw,
                              const float* __restrict__ pjw, _Float16* __restrict__ wAll,
                              float* __restrict__ zp)
{
    int bid = blockIdx.x, tid = threadIdx.x;
    if (bid < 8192) {
        size_t i = ((size_t)bid*256 + tid) * 4;
        float4 v = *(const float4*)&src[i];
        f16x4 o; o[0] = (_Float16)v.x; o[1] = (_Float16)v.y; o[2] = (_Float16)v.z; o[3] = (_Float16)v.w;
        *(f16x4*)&dst[i] = o;
    } else if (bid < 8512) {
        int i = (bid - 8192)*256 + tid;  // < 81920
        float v = (i < 49152) ? ipw[i] : (i < 65536 ? opw[i - 49152] : pjw[i - 65536]);
        wAll[i] = (_Float16)v;
    } else {
        int i = (bid - 8512)*256 + tid;  // zero 20348 floats = 5087 float4
        if (i < 5087) {
            float4 z = {0.f, 0.f, 0.f, 0.f};
            *(float4*)&zp[i*4] = z;
        }
    }
}

// ---------------------------------------------------------------- K2: pointwise GEMM + gelu + mean
// R11 verified version: LDS-staged (gload16, linear dest, src/read slot-XOR),
// operand-swapped MFMA (D-rows = t in regs, D-cols = o in lanes), in-register t-sum.
__global__ __launch_bounds__(256) void pw_kernel(const _Float16* __restrict__ W,
                                                 const _Float16* __restrict__ Gt,
                                                 const float* __restrict__ pwb,
                                                 float* __restrict__ xmean)
{
    __shared__ __align__(16) _Float16 As[2][128][32];  // 16KB
    __shared__ __align__(16) _Float16 Bs[2][128][32];  // 16KB

    int x = blockIdx.x;
    int xcd = x & 7, ii = x >> 3;
    int ob = xcd * 32 + (ii >> 4);   // o-block: slow
    int b  = ii & 15;                // batch: fast (A-tile L2 reuse)
    const _Float16* Arow = W  + (size_t)ob * 128 * 256;
    const _Float16* Brow = Gt + (size_t)b  * 128 * 256;

    int tid = threadIdx.x, w = tid >> 6, l = tid & 63, lr = l & 15, lk = l >> 4;
    int wr = w >> 1, wc = w & 1;
    int rsw = (lr >> 1) & 3;                 // read-slot XOR key

    f32x4 acc[4][4];
    #pragma unroll
    for (int i = 0; i < 4; ++i)
        #pragma unroll
        for (int j = 0; j < 4; ++j)
            acc[i][j] = f32x4{0.f, 0.f, 0.f, 0.f};

    auto stage = [&](int buf, int k0) {
        #pragma unroll
        for (int j = 0; j < 2; ++j) {
            int chunk = tid + j*256;          // 0..511; LDS dest = chunk*16B (linear)
            int row = chunk >> 2;
            int co  = (chunk & 3) * 8;                        // dest col (halves)
            int cos = ((chunk & 3) ^ ((chunk >> 3) & 3)) * 8; // swizzled source col
            gload16(&Arow[row*256 + k0 + cos], &As[buf][row][co]);
            gload16(&Brow[row*256 + k0 + cos], &Bs[buf][row][co]);
        }
    };

    stage(0, 0);
    __syncthreads();
    for (int ks = 0; ks < 8; ++ks) {
        int cur = ks & 1;
        if (ks < 7) stage(cur ^ 1, (ks + 1) * 32);
        f16x8 a[4], bb[4];
        #pragma unroll
        for (int i = 0; i < 4; ++i)
            a[i]  = *(const f16x8*)&As[cur][wr*64 + i*16 + lr][(lk ^ rsw)*8];
        #pragma unroll
        for (int j = 0; j < 4; ++j)
            if (wc == 0 || j < 3)            // wc=1, j=3 -> t=112..127 all padding
                bb[j] = *(const f16x8*)&Bs[cur][wc*64 + j*16 + lr][(lk ^ rsw)*8];
        #pragma unroll
        for (int i = 0; i < 4; ++i)
            #pragma unroll
            for (int j = 0; j < 4; ++j)
                if (wc == 0 || j < 3)
                    acc[i][j] = __builtin_amdgcn_mfma_f32_16x16x32_f16(bb[j], a[i], acc[i][j], 0, 0, 0);
        __syncthreads();
    }

    // epilogue: per lane o = wr*64+i*16+lr; t-values live in (j, lk, r)
    float (*red)[2] = reinterpret_cast<float(*)[2]>(&As[0][0][0]);
    #pragma unroll
    for (int i = 0; i < 4; ++i) {
        int og = ob*128 + wr*64 + i*16 + lr;
        float pbv = pwb[og];
        float s = 0.f;
        if (wc == 0) {
            #pragma unroll
            for (int j = 0; j < 4; ++j)
                #pragma unroll
                for (int r = 0; r < 4; ++r)
                    s += gelu_f(acc[i][j][r] + pbv);      // t = j*16+lk*4+r <= 63, all live
        } else {
            #pragma unroll
            for (int j = 0; j < 2; ++j)
                #pragma unroll
                for (int r = 0; r < 4; ++r)
                    s += gelu_f(acc[i][j][r] + pbv);      // t = 64..95, all live
            if (lk == 0) s += gelu_f(acc[i][2][0] + pbv); // t = 96 only
        }
        s += __shfl_xor(s, 16, 64);
        s += __shfl_xor(s, 32, 64);
        if (lk == 0) red[wr*64 + i*16 + lr][wc] = s;
    }
    __syncthreads();
    if (tid < 128) {
        float v = (red[tid][0] + red[tid][1]) * (1.f / 97.f);
        xmean[(size_t)b*32768 + ob*128 + tid] = v;
    }
}

// ---------------------------------------------------------------- K3: layernorm (+q out, q hi/lo f16, ||q||^2)
__global__ void ln_kernel(const float* __restrict__ xm, const float* __restrict__ g,
                          const float* __restrict__ bta, float* __restrict__ qout,
                          _Float16* __restrict__ qh, _Float16* __restrict__ qlo,
                          float* __restrict__ qss)
{
    int bn = blockIdx.x, lane = threadIdx.x;  // 64 threads
    float x0 = xm[(size_t)bn*128 + lane];
    float x1 = xm[(size_t)bn*128 + 64 + lane];
    float s = x0 + x1;
    #pragma unroll
    for (int m = 1; m < 64; m <<= 1) s += __shfl_xor(s, m, 64);
    float mu = s * (1.f/128.f);
    float d0 = x0 - mu, d1 = x1 - mu;
    float v = d0*d0 + d1*d1;
    #pragma unroll
    for (int m = 1; m < 64; m <<= 1) v += __shfl_xor(v, m, 64);
    float rs = 1.0f / sqrtf(v * (1.f/128.f) + 1e-5f);
    float q0 = d0*rs*g[lane]    + bta[lane];
    float q1 = d1*rs*g[64+lane] + bta[64+lane];
    qout[(size_t)bn*128 + lane]      = q0;
    qout[(size_t)bn*128 + 64 + lane] = q1;
    _Float16 h0 = (_Float16)q0, h1 = (_Float16)q1;
    qh[(size_t)bn*128 + lane]      = h0;
    qh[(size_t)bn*128 + 64 + lane] = h1;
    qlo[(size_t)bn*128 + lane]      = (_Float16)(q0 - (float)h0);
    qlo[(size_t)bn*128 + 64 + lane] = (_Float16)(q1 - (float)h1);
    float ss = q0*q0 + q1*q1;
    #pragma unroll
    for (int m = 1; m < 64; m <<= 1) ss += __shfl_xor(ss, m, 64);
    if (lane == 0) atomicAdd(&qss[bn >> 8], ss);
}

// ---------------------------------------------------------------- K4: similarity via MFMA, LDS-staged mem
// (unchanged from R11)
__global__ __launch_bounds__(256) void simgemm_kernel(const _Float16* __restrict__ qhi,
                                                      const _Float16* __restrict__ qlo,
                                                      const float* __restrict__ mem,
                                                      float* __restrict__ dotp,
                                                      float* __restrict__ mn2)
{
    __shared__ __align__(16) float Ms[2][16][256];   // 16KB per buf
    __shared__ f32x4 redls[4][64];
    __shared__ float redn[4][16];

    int tid = threadIdx.x, w = tid >> 6, l = tid & 63, lr = l & 15, lk = l >> 4;
    int m0 = blockIdx.y * 16;
    int kwin = blockIdx.x * 1024;
    int rowm = m0 + lr;

    auto stage = [&](int buf, int sw) {
        #pragma unroll
        for (int j = 0; j < 4; ++j) {
            int r = w*4 + j;                          // local row, wave-uniform
            int rowg = m0 + r; if (rowg > 1195) rowg = 1195;
            const float* src = mem + (size_t)rowg*32768 + kwin + sw*256 + (l ^ (r & 7))*4;
            gload16(src, &Ms[buf][r][0]);             // + lane*16B by HW
        }
    };

    f32x4 acc_a = {0.f,0.f,0.f,0.f}, acc_b = {0.f,0.f,0.f,0.f};
    float nacc = 0.f;

    stage(0, 0);
    __syncthreads();
    for (int sw = 0; sw < 4; ++sw) {
        int cur = sw & 1;
        if (sw < 3) stage(cur ^ 1, sw + 1);
        #pragma unroll
        for (int cc = 0; cc < 2; ++cc) {
            int kl = w*64 + cc*32;                    // k within sub-window
            int s0 = (kl + lk*8) >> 2;                // 16B slot 0..62
            float4 v0 = *(const float4*)&Ms[cur][lr][(s0       ^ (lr & 7))*4];
            float4 v1 = *(const float4*)&Ms[cur][lr][((s0 + 1) ^ (lr & 7))*4];
            int kg = kwin + sw*256 + kl + lk*8;
            f16x8 ah = *(const f16x8*)&qhi[(size_t)lr*32768 + kg];
            f16x8 al = *(const f16x8*)&qlo[(size_t)lr*32768 + kg];
            float e0 = v0.x, e1 = v0.y, e2 = v0.z, e3 = v0.w;
            float e4 = v1.x, e5 = v1.y, e6 = v1.z, e7 = v1.w;
            f16x8 bh;
            bh[0]=(_Float16)e0; bh[1]=(_Float16)e1; bh[2]=(_Float16)e2; bh[3]=(_Float16)e3;
            bh[4]=(_Float16)e4; bh[5]=(_Float16)e5; bh[6]=(_Float16)e6; bh[7]=(_Float16)e7;
            nacc = fmaf(e0,e0, fmaf(e1,e1, fmaf(e2,e2, fmaf(e3,e3, nacc))));
            nacc = fmaf(e4,e4, fmaf(e5,e5, fmaf(e6,e6, fmaf(e7,e7, nacc))));
            acc_a = __builtin_amdgcn_mfma_f32_16x16x32_f16(ah, bh, acc_a, 0, 0, 0);
            acc_b = __builtin_amdgcn_mfma_f32_16x16x32_f16(al, bh, acc_b, 0, 0, 0);
        }
        __syncthreads();
    }

    // mem row norms within wave (lanes lr,lr+16,lr+32,lr+48 share a row)
    nacc += __shfl_xor(nacc, 16, 64);
    nacc += __shfl_xor(nacc, 32, 64);

    // cross-wave reduction, one atomic set per block
    f32x4 tot = acc_a + acc_b;
    redls[w][l] = tot;
    if (lk == 0) redn[w][lr] = nacc;
    __syncthreads();
    if (w == 0) {
        tot = redls[0][l];
        tot += redls[1][l]; tot += redls[2][l]; tot += redls[3][l];
        if (rowm < 1196) {
            #pragma unroll
            for (int r = 0; r < 4; ++r)
                atomicAdd(&dotp[(lk*4 + r)*1196 + rowm], tot[r]);
            if (lk == 0)
                atomicAdd(&mn2[rowm], redn[0][lr] + redn[1][lr] + redn[2][lr] + redn[3][lr]);
        }
    }
}

// ---------------------------------------------------------------- K5: finalize sim + top-8
__global__ void topk_kernel(const float* __restrict__ dotp, const float* __restrict__ mn2,
                            const float* __restrict__ qss, const int* __restrict__ seaq,
                            const float* __restrict__ yq, const int* __restrict__ seam,
                            const float* __restrict__ ym, int* __restrict__ idx)
{
    __shared__ float sc[1216];
    int b = blockIdx.x, lane = threadIdx.x;  // 64 threads
    float qn = fmaxf(sqrtf(qss[b]), 1e-12f);
    int sq = seaq[b];
    float yqv = yq[b];
    for (int m = lane; m < 1216; m += 64) {
        float v = -3e38f;
        if (m < 1196) {
            float s = dotp[b*1196 + m] / (qn * fmaxf(sqrtf(mn2[m]), 1e-12f));
            if (seam[m] != sq) s = -10000.0f;
            float dy = fabsf(yqv - ym[m]);
            v = s * (1.0f - 0.5f * expf(-0.5f * dy));
        }
        sc[m] = v;
    }
    __syncthreads();
    for (int kk = 0; kk < 8; ++kk) {
        float bv = -3e38f; int bi = 0x7fffffff;
        for (int m = lane; m < 1216; m += 64) {
            float v = sc[m];
            if (v > bv) { bv = v; bi = m; }
        }
        #pragma unroll
        for (int mk = 1; mk < 64; mk <<= 1) {
            float ov = __shfl_xor(bv, mk, 64);
            int   oi = __shfl_xor(bi, mk, 64);
            if (ov > bv || (ov == bv && oi < bi)) { bv = ov; bi = oi; }
        }
        if (lane == 0) { idx[b*8 + kk] = bi; sc[bi] = -3e38f; }
        __syncthreads();
    }
}

// ---------------------------------------------------------------- merged q/k/v projection (grid 64+512+512)
// K/V branches gather directly from memory_bank rows via idx (f32 -> f16 inline);
// the kvg intermediate and gather kernel are gone. All 64 rows a block touches
// share one bk -> idx load is wave-uniform scalar.
__global__ __launch_bounds__(256) void qkv_kernel(const _Float16* __restrict__ qh,
                                                  const float* __restrict__ memb,
                                                  const int* __restrict__ idx,
                                                  const _Float16* __restrict__ wAll,
                                                  const float* __restrict__ ipb,
                                                  _Float16* __restrict__ qp,
                                                  _Float16* __restrict__ kp,
                                                  _Float16* __restrict__ vp)
{
    int bid = blockIdx.x;
    const _Float16* Wm; const float* bias; _Float16* Y; int blk; int kv;
    if (bid < 64)       { kv = 0; Wm = wAll;         bias = ipb;       Y = qp; blk = bid; }
    else if (bid < 576) { kv = 1; Wm = wAll + 16384; bias = ipb + 128; Y = kp; blk = bid - 64; }
    else                { kv = 1; Wm = wAll + 32768; bias = ipb + 256; Y = vp; blk = bid - 576; }

    int tid = threadIdx.x, w = tid >> 6, l = tid & 63, lr = l & 15, lk = l >> 4;
    int r0 = blk * 64 + w * 16;

    const float* Af = nullptr;
    const _Float16* Ah = nullptr;
    if (kv) {
        int bk = (blk * 64) >> 8;            // block-uniform (64-row tile within 256-row bk)
        int row = idx[bk];                   // retrieved memory row
        Af = memb + (size_t)row*32768 + ((r0 & 255) + lr)*128 + lk*8;
    } else {
        Ah = qh + (size_t)(r0 + lr)*128 + lk*8;
    }

    f32x4 acc[8];
    #pragma unroll
    for (int j = 0; j < 8; ++j) acc[j] = f32x4{0.f, 0.f, 0.f, 0.f};
    #pragma unroll
    for (int k0 = 0; k0 < 128; k0 += 32) {
        f16x8 a;
        if (kv) {
            float4 v0 = *(const float4*)&Af[k0];
            float4 v1 = *(const float4*)&Af[k0 + 4];
            a[0]=(_Float16)v0.x; a[1]=(_Float16)v0.y; a[2]=(_Float16)v0.z; a[3]=(_Float16)v0.w;
            a[4]=(_Float16)v1.x; a[5]=(_Float16)v1.y; a[6]=(_Float16)v1.z; a[7]=(_Float16)v1.w;
        } else {
            a = *(const f16x8*)&Ah[k0];
        }
        #pragma unroll
        for (int j = 0; j < 8; ++j) {
            f16x8 bb = *(const f16x8*)&Wm[(j*16 + lr)*128 + k0 + lk*8];
            acc[j] = __builtin_amdgcn_mfma_f32_16x16x32_f16(a, bb, acc[j], 0, 0, 0);
        }
    }
    #pragma unroll
    for (int j = 0; j < 8; ++j) {
        #pragma unroll
        for (int r = 0; r < 4; ++r) {
            int row = r0 + lk*4 + r, col = j*16 + lr;
            Y[(size_t)row*128 + col] = (_Float16)(acc[j][r] + bias[col]);
        }
    }
}

// ---------------------------------------------------------------- generic (R x 128) @ W[128][128]^T + bias
template<int OUT_F32>
__global__ __launch_bounds__(256) void gemm128_kernel(const _Float16* __restrict__ A,
                                                      const _Float16* __restrict__ W,
                                                      const float* __restrict__ bias,
                                                      void* __restrict__ Y, int R)
{
    int tid = threadIdx.x, w = tid >> 6, l = tid & 63, lr = l & 15, lk = l >> 4;
    int r0 = blockIdx.x * 64 + w * 16;
    f32x4 acc[8];
    #pragma unroll
    for (int j = 0; j < 8; ++j) acc[j] = f32x4{0.f, 0.f, 0.f, 0.f};
    #pragma unroll
    for (int k0 = 0; k0 < 128; k0 += 32) {
        f16x8 a = *(const f16x8*)&A[(size_t)(r0 + lr)*128 + k0 + lk*8];
        #pragma unroll
        for (int j = 0; j < 8; ++j) {
            f16x8 bb = *(const f16x8*)&W[(j*16 + lr)*128 + k0 + lk*8];
            acc[j] = __builtin_amdgcn_mfma_f32_16x16x32_f16(a, bb, acc[j], 0, 0, 0);
        }
    }
    #pragma unroll
    for (int j = 0; j < 8; ++j) {
        #pragma unroll
        for (int r = 0; r < 4; ++r) {
            int row = r0 + lk*4 + r, col = j*16 + lr;
            float v = acc[j][r] + bias[col];
            if (OUT_F32) ((float*)Y)[(size_t)row*128 + col] = v;
            else         ((_Float16*)Y)[(size_t)row*128 + col] = (_Float16)v;
        }
    }
}

// ---------------------------------------------------------------- K8: 8-key attention
__global__ void attn_kernel(const _Float16* __restrict__ qp, const _Float16* __restrict__ kp,
                            const _Float16* __restrict__ vp, _Float16* __restrict__ ctx)
{
    int bn = blockIdx.x;                 // b*256+n
    int b = bn >> 8, n = bn & 255;
    int tid = threadIdx.x;               // 128, d = tid, h = tid>>5
    float qv = (float)qp[(size_t)bn*128 + tid];
    float sc[8];
    #pragma unroll
    for (int k = 0; k < 8; ++k) {
        float p = qv * (float)kp[(((size_t)(b*8 + k)*256 + n)*128) + tid];
        #pragma unroll
        for (int m = 1; m < 32; m <<= 1) p += __shfl_xor(p, m, 64);
        sc[k] = p * 0.17677669529663687f;   // 1/sqrt(32)
    }
    float mx = sc[0];
    #pragma unroll
    for (int k = 1; k < 8; ++k) mx = fmaxf(mx, sc[k]);
    float den = 0.f;
    #pragma unroll
    for (int k = 0; k < 8; ++k) { sc[k] = expf(sc[k] - mx); den += sc[k]; }
    float inv = 1.f / den;
    float c = 0.f;
    #pragma unroll
    for (int k = 0; k < 8; ++k)
        c += sc[k] * (float)vp[(((size_t)(b*8 + k)*256 + n)*128) + tid];
    ctx[(size_t)bn*128 + tid] = (_Float16)(c * inv);
}

// ================================================================ launch
extern "C" void kernel_launch(void* const* d_in, const int* in_sizes, int n_in,
                              void* d_out, int out_size, void* d_ws, size_t ws_size,
                              hipStream_t stream)
{
    const float* x_scalar = (const float*)d_in[0];
    const int*   season_q = (const int*)d_in[1];
    const float* year_q   = (const float*)d_in[2];
    const float* dw_w     = (const float*)d_in[3];
    const float* dw_b     = (const float*)d_in[4];
    const float* pw_w     = (const float*)d_in[5];
    const float* pw_b     = (const float*)d_in[6];
    const float* ln_g     = (const float*)d_in[7];
    const float* ln_b     = (const float*)d_in[8];
    const float* memb     = (const float*)d_in[9];
    const int*   mseas    = (const int*)d_in[10];
    const float* myear    = (const float*)d_in[11];
    const float* ipw      = (const float*)d_in[12];
    const float* ipb      = (const float*)d_in[13];
    const float* opw      = (const float*)d_in[14];
    const float* opb      = (const float*)d_in[15];
    const float* pjw      = (const float*)d_in[16];
    const float* pjb      = (const float*)d_in[17];

    char* wsb = (char*)d_ws;
    _Float16* Wf   = (_Float16*)(wsb + 0);            // 16,777,216
    _Float16* Gt   = (_Float16*)(wsb + 16777216);     //  1,048,576
    float*    xmean= (float*)   (wsb + 17825792);     //  2,097,152
    _Float16* qh   = (_Float16*)(wsb + 19922944);     //  1,048,576
    float*    qss  = (float*)   (wsb + 20971520);     //        64
    float*    dotp = (float*)   (wsb + 20971584);     //     76,544
    float*    mn2  = (float*)   (wsb + 21048128);     //      4,784
    int*      idxb = (int*)     (wsb + 21052928);     //        512
    _Float16* qp   = (_Float16*)(wsb + 29442048);     //  1,048,576
    _Float16* kp   = (_Float16*)(wsb + 30490624);     //  8,388,608
    _Float16* vp   = (_Float16*)(wsb + 38879232);     //  8,388,608
    _Float16* ctx  = (_Float16*)(wsb + 47267840);     //  1,048,576
    _Float16* out1 = (_Float16*)(wsb + 48316416);     //  1,048,576
    _Float16* wAll = (_Float16*)(wsb + 49364992);     //    163,840  (wq|wk|wv|wo|wp)
    _Float16* qlo  = (_Float16*)(wsb + 49528832);     //  1,048,576

    float* outp = (float*)d_out;
    float* qout = (float*)d_out + 524288;

    // merged: pw_w->f16 | small weights->f16 | zero accumulators
    cvt_pw_kernel<<<8532, 256, 0, stream>>>(pw_w, Wf, ipw, opw, pjw, wAll,
                                            (float*)(wsb + 20971520));
    conv_kernel<<<dim3(16, 128), 256, 0, stream>>>(x_scalar, dw_w, dw_b, Gt);

    // big fused pointwise GEMM + gelu + mean (R11 staged version)
    pw_kernel<<<4096, 256, 0, stream>>>(Wf, Gt, pw_b, xmean);

    // layernorm -> q (f32 to d_out, f16 hi/lo, ||q||^2)
    ln_kernel<<<4096, 64, 0, stream>>>(xmean, ln_g, ln_b, qout, qh, qlo, qss);

    // similarity via MFMA + norms, then masked/diversity top-8
    simgemm_kernel<<<dim3(32, 75), 256, 0, stream>>>(qh, qlo, memb, dotp, mn2);
    topk_kernel<<<16, 64, 0, stream>>>(dotp, mn2, qss, season_q, year_q, mseas, myear, idxb);

    // merged q/k/v projections (K/V gather directly from memory_bank via idx)
    qkv_kernel<<<1088, 256, 0, stream>>>(qh, memb, idxb, wAll, ipb, qp, kp, vp);

    // attention
    attn_kernel<<<4096, 128, 0, stream>>>(qp, kp, vp, ctx);

    // output projections
    gemm128_kernel<0><<<64, 256, 0, stream>>>(ctx,  wAll + 49152, opb, (void*)out1, 4096);
    gemm128_kernel<1><<<64, 256, 0, stream>>>(out1, wAll + 65536, pjb, (void*)outp, 4096);
}

// Round 14
// 203.604 us; speedup vs baseline: 1.5313x; 1.1975x over previous
//
#include <hip/hip_runtime.h>

typedef _Float16 f16x8 __attribute__((ext_vector_type(8)));
typedef _Float16 f16x4 __attribute__((ext_vector_type(4)));
typedef float    f32x4 __attribute__((ext_vector_type(4)));

// exact-erf GELU via Abramowitz-Stegun 7.1.26 (|erf err| <= 1.5e-7), ~14 VALU ops
__device__ __forceinline__ float gelu_f(float x) {
    float z  = 0.70710678118654752440f * x;
    float az = fabsf(z);
    float t  = 1.0f / fmaf(0.3275911f, az, 1.0f);
    float e  = __expf(-az * az);
    float p  = t * fmaf(t, fmaf(t, fmaf(t, fmaf(t, 1.061405429f, -1.453152027f),
                                        1.421413741f), -0.284496736f), 0.254829592f);
    float er = fmaf(-p, e, 1.0f);          // erf(|z|)
    float s  = (z < 0.0f) ? -er : er;      // erf(z), odd
    return 0.5f * x * (1.0f + s);
}

// async global->LDS, 16B per lane (dest = wave-uniform base + lane*16)
__device__ __forceinline__ void gload16(const void* g, void* l) {
    __builtin_amdgcn_global_load_lds(
        (const __attribute__((address_space(1))) unsigned int*)g,
        (__attribute__((address_space(3))) unsigned int*)l, 16, 0, 0);
}

// ---------------------------------------------------------------- K1: conv+gelu
__global__ void conv_kernel(const float* __restrict__ xs, const float* __restrict__ dww,
                            const float* __restrict__ dwb, _Float16* __restrict__ Gt)
{
    int b = blockIdx.x, t = blockIdx.y, n = threadIdx.x;
    float g = 0.f;
    if (t < 97) {
        float y = 0.f;
        #pragma unroll
        for (int j = 0; j < 12; ++j) {
            int tt = t + j - 6;
            if (tt >= 0 && tt < 96)
                y += dww[n*12 + j] * xs[((size_t)b*96 + tt)*256 + n];
        }
        g = gelu_f(y + dwb[n]);
    }
    Gt[((size_t)b*128 + t)*256 + n] = (_Float16)g;
}

// ---------------------------------------------------------------- K-cvt (merged: pw_w cvt | small-w cvt | zero | Wc=pjw@opw)
__global__ void cvt_pw_kernel(const float* __restrict__ src, _Float16* __restrict__ dst,
                              const float* __restrict__ ipw, const float* __restrict__ opw,
                              const float* __restrict__ pjw, const float* __restrict__ opb,
                              const float* __restrict__ pjb, _Float16* __restrict__ wAll,
                              float* __restrict__ zp, _Float16* __restrict__ Wcf,
                              float* __restrict__ bc)
{
    int bid = blockIdx.x, tid = threadIdx.x;
    if (bid < 8192) {
        size_t i = ((size_t)bid*256 + tid) * 4;
        float4 v = *(const float4*)&src[i];
        f16x4 o; o[0] = (_Float16)v.x; o[1] = (_Float16)v.y; o[2] = (_Float16)v.z; o[3] = (_Float16)v.w;
        *(f16x4*)&dst[i] = o;
    } else if (bid < 8512) {
        int i = (bid - 8192)*256 + tid;  // < 81920 (wq|wk|wv only used up to 49152; rest harmless)
        float v = (i < 49152) ? ipw[i] : (i < 65536 ? opw[i - 49152] : pjw[i - 65536]);
        wAll[i] = (_Float16)v;
    } else if (bid < 8532) {
        int i = (bid - 8512)*256 + tid;  // zero 20348 floats = 5087 float4
        if (i < 5087) {
            float4 z = {0.f, 0.f, 0.f, 0.f};
            *(float4*)&zp[i*4] = z;
        }
    } else {
        // Wc[e][c] = sum_d pjw[e][d] * opw[d][c]  (combined out-projection), f16
        int e = (bid - 8532)*2 + (tid >> 7);
        int c = tid & 127;
        float acc = 0.f;
        for (int d = 0; d < 128; ++d)
            acc = fmaf(pjw[e*128 + d], opw[d*128 + c], acc);
        Wcf[e*128 + c] = (_Float16)acc;
        if (c == 0) {
            float s = pjb[e];
            for (int d = 0; d < 128; ++d)
                s = fmaf(pjw[e*128 + d], opb[d], s);
            bc[e] = s;
        }
    }
}

// ---------------------------------------------------------------- K2: pointwise GEMM + gelu + mean + LAYERNORM
// R11 GEMM structure (LDS-staged gload16, operand-swapped MFMA, in-register t-sum).
// New: block (ob,b) owns exactly LN-row (b, n=ob) -> LN fused in epilogue; writes
// qout (f32, d_out), qh/qlo (f16 hi/lo split), qss (||q||^2 per b). xmean gone.
__global__ __launch_bounds__(256) void pw_kernel(const _Float16* __restrict__ W,
                                                 const _Float16* __restrict__ Gt,
                                                 const float* __restrict__ pwb,
                                                 const float* __restrict__ lng,
                                                 const float* __restrict__ lnb,
                                                 float* __restrict__ qout,
                                                 _Float16* __restrict__ qh,
                                                 _Float16* __restrict__ qlo,
                                                 float* __restrict__ qss)
{
    __shared__ __align__(16) _Float16 As[2][128][32];  // 16KB
    __shared__ __align__(16) _Float16 Bs[2][128][32];  // 16KB

    int x = blockIdx.x;
    int xcd = x & 7, ii = x >> 3;
    int ob = xcd * 32 + (ii >> 4);   // o-block = n (slow)
    int b  = ii & 15;                // batch (fast, A-tile L2 reuse)
    const _Float16* Arow = W  + (size_t)ob * 128 * 256;
    const _Float16* Brow = Gt + (size_t)b  * 128 * 256;

    int tid = threadIdx.x, w = tid >> 6, l = tid & 63, lr = l & 15, lk = l >> 4;
    int wr = w >> 1, wc = w & 1;
    int rsw = (lr >> 1) & 3;                 // read-slot XOR key

    f32x4 acc[4][4];
    #pragma unroll
    for (int i = 0; i < 4; ++i)
        #pragma unroll
        for (int j = 0; j < 4; ++j)
            acc[i][j] = f32x4{0.f, 0.f, 0.f, 0.f};

    auto stage = [&](int buf, int k0) {
        #pragma unroll
        for (int j = 0; j < 2; ++j) {
            int chunk = tid + j*256;          // 0..511; LDS dest = chunk*16B (linear)
            int row = chunk >> 2;
            int co  = (chunk & 3) * 8;                        // dest col (halves)
            int cos = ((chunk & 3) ^ ((chunk >> 3) & 3)) * 8; // swizzled source col
            gload16(&Arow[row*256 + k0 + cos], &As[buf][row][co]);
            gload16(&Brow[row*256 + k0 + cos], &Bs[buf][row][co]);
        }
    };

    stage(0, 0);
    __syncthreads();
    for (int ks = 0; ks < 8; ++ks) {
        int cur = ks & 1;
        if (ks < 7) stage(cur ^ 1, (ks + 1) * 32);
        f16x8 a[4], bb[4];
        #pragma unroll
        for (int i = 0; i < 4; ++i)
            a[i]  = *(const f16x8*)&As[cur][wr*64 + i*16 + lr][(lk ^ rsw)*8];
        #pragma unroll
        for (int j = 0; j < 4; ++j)
            if (wc == 0 || j < 3)            // wc=1, j=3 -> t=112..127 all padding
                bb[j] = *(const f16x8*)&Bs[cur][wc*64 + j*16 + lr][(lk ^ rsw)*8];
        #pragma unroll
        for (int i = 0; i < 4; ++i)
            #pragma unroll
            for (int j = 0; j < 4; ++j)
                if (wc == 0 || j < 3)
                    acc[i][j] = __builtin_amdgcn_mfma_f32_16x16x32_f16(bb[j], a[i], acc[i][j], 0, 0, 0);
        __syncthreads();
    }

    // epilogue: per lane o = wr*64+i*16+lr; t-values live in (j, lk, r)
    float (*red)[2] = reinterpret_cast<float(*)[2]>(&As[0][0][0]);
    #pragma unroll
    for (int i = 0; i < 4; ++i) {
        int og = ob*128 + wr*64 + i*16 + lr;
        float pbv = pwb[og];
        float s = 0.f;
        if (wc == 0) {
            #pragma unroll
            for (int j = 0; j < 4; ++j)
                #pragma unroll
                for (int r = 0; r < 4; ++r)
                    s += gelu_f(acc[i][j][r] + pbv);      // t = j*16+lk*4+r <= 63
        } else {
            #pragma unroll
            for (int j = 0; j < 2; ++j)
                #pragma unroll
                for (int r = 0; r < 4; ++r)
                    s += gelu_f(acc[i][j][r] + pbv);      // t = 64..95
            if (lk == 0) s += gelu_f(acc[i][2][0] + pbv); // t = 96 only
        }
        s += __shfl_xor(s, 16, 64);
        s += __shfl_xor(s, 32, 64);
        if (lk == 0) red[wr*64 + i*16 + lr][wc] = s;
    }
    __syncthreads();

    // fused layernorm over the block's 128 o-values (= LN row (b, n=ob)); wave 0 only
    if (w == 0) {
        float x0 = (red[l][0]      + red[l][1])      * (1.f/97.f);
        float x1 = (red[64 + l][0] + red[64 + l][1]) * (1.f/97.f);
        float sm = x0 + x1;
        #pragma unroll
        for (int m = 1; m < 64; m <<= 1) sm += __shfl_xor(sm, m, 64);
        float mu = sm * (1.f/128.f);
        float d0 = x0 - mu, d1 = x1 - mu;
        float vv = d0*d0 + d1*d1;
        #pragma unroll
        for (int m = 1; m < 64; m <<= 1) vv += __shfl_xor(vv, m, 64);
        float rs = 1.0f / sqrtf(vv * (1.f/128.f) + 1e-5f);
        float q0 = d0*rs*lng[l]      + lnb[l];
        float q1 = d1*rs*lng[64 + l] + lnb[64 + l];
        size_t bn = (size_t)b*256 + ob;
        qout[bn*128 + l]      = q0;
        qout[bn*128 + 64 + l] = q1;
        _Float16 h0 = (_Float16)q0, h1 = (_Float16)q1;
        qh[bn*128 + l]       = h0;
        qh[bn*128 + 64 + l]  = h1;
        qlo[bn*128 + l]      = (_Float16)(q0 - (float)h0);
        qlo[bn*128 + 64 + l] = (_Float16)(q1 - (float)h1);
        float ss = q0*q0 + q1*q1;
        #pragma unroll
        for (int m = 1; m < 64; m <<= 1) ss += __shfl_xor(ss, m, 64);
        if (l == 0) atomicAdd(&qss[b], ss);
    }
}

// ---------------------------------------------------------------- K4: similarity via MFMA, LDS-staged mem
// (unchanged from R11/R13)
__global__ __launch_bounds__(256) void simgemm_kernel(const _Float16* __restrict__ qhi,
                                                      const _Float16* __restrict__ qlo,
                                                      const float* __restrict__ mem,
                                                      float* __restrict__ dotp,
                                                      float* __restrict__ mn2)
{
    __shared__ __align__(16) float Ms[2][16][256];   // 16KB per buf
    __shared__ f32x4 redls[4][64];
    __shared__ float redn[4][16];

    int tid = threadIdx.x, w = tid >> 6, l = tid & 63, lr = l & 15, lk = l >> 4;
    int m0 = blockIdx.y * 16;
    int kwin = blockIdx.x * 1024;
    int rowm = m0 + lr;

    auto stage = [&](int buf, int sw) {
        #pragma unroll
        for (int j = 0; j < 4; ++j) {
            int r = w*4 + j;                          // local row, wave-uniform
            int rowg = m0 + r; if (rowg > 1195) rowg = 1195;
            const float* src = mem + (size_t)rowg*32768 + kwin + sw*256 + (l ^ (r & 7))*4;
            gload16(src, &Ms[buf][r][0]);             // + lane*16B by HW
        }
    };

    f32x4 acc_a = {0.f,0.f,0.f,0.f}, acc_b = {0.f,0.f,0.f,0.f};
    float nacc = 0.f;

    stage(0, 0);
    __syncthreads();
    for (int sw = 0; sw < 4; ++sw) {
        int cur = sw & 1;
        if (sw < 3) stage(cur ^ 1, sw + 1);
        #pragma unroll
        for (int cc = 0; cc < 2; ++cc) {
            int kl = w*64 + cc*32;                    // k within sub-window
            int s0 = (kl + lk*8) >> 2;                // 16B slot 0..62
            float4 v0 = *(const float4*)&Ms[cur][lr][(s0       ^ (lr & 7))*4];
            float4 v1 = *(const float4*)&Ms[cur][lr][((s0 + 1) ^ (lr & 7))*4];
            int kg = kwin + sw*256 + kl + lk*8;
            f16x8 ah = *(const f16x8*)&qhi[(size_t)lr*32768 + kg];
            f16x8 al = *(const f16x8*)&qlo[(size_t)lr*32768 + kg];
            float e0 = v0.x, e1 = v0.y, e2 = v0.z, e3 = v0.w;
            float e4 = v1.x, e5 = v1.y, e6 = v1.z, e7 = v1.w;
            f16x8 bh;
            bh[0]=(_Float16)e0; bh[1]=(_Float16)e1; bh[2]=(_Float16)e2; bh[3]=(_Float16)e3;
            bh[4]=(_Float16)e4; bh[5]=(_Float16)e5; bh[6]=(_Float16)e6; bh[7]=(_Float16)e7;
            nacc = fmaf(e0,e0, fmaf(e1,e1, fmaf(e2,e2, fmaf(e3,e3, nacc))));
            nacc = fmaf(e4,e4, fmaf(e5,e5, fmaf(e6,e6, fmaf(e7,e7, nacc))));
            acc_a = __builtin_amdgcn_mfma_f32_16x16x32_f16(ah, bh, acc_a, 0, 0, 0);
            acc_b = __builtin_amdgcn_mfma_f32_16x16x32_f16(al, bh, acc_b, 0, 0, 0);
        }
        __syncthreads();
    }

    // mem row norms within wave (lanes lr,lr+16,lr+32,lr+48 share a row)
    nacc += __shfl_xor(nacc, 16, 64);
    nacc += __shfl_xor(nacc, 32, 64);

    // cross-wave reduction, one atomic set per block
    f32x4 tot = acc_a + acc_b;
    redls[w][l] = tot;
    if (lk == 0) redn[w][lr] = nacc;
    __syncthreads();
    if (w == 0) {
        tot = redls[0][l];
        tot += redls[1][l]; tot += redls[2][l]; tot += redls[3][l];
        if (rowm < 1196) {
            #pragma unroll
            for (int r = 0; r < 4; ++r)
                atomicAdd(&dotp[(lk*4 + r)*1196 + rowm], tot[r]);
            if (lk == 0)
                atomicAdd(&mn2[rowm], redn[0][lr] + redn[1][lr] + redn[2][lr] + redn[3][lr]);
        }
    }
}

// ---------------------------------------------------------------- K5: finalize sim + top-8
__global__ void topk_kernel(const float* __restrict__ dotp, const float* __restrict__ mn2,
                            const float* __restrict__ qss, const int* __restrict__ seaq,
                            const float* __restrict__ yq, const int* __restrict__ seam,
                            const float* __restrict__ ym, int* __restrict__ idx)
{
    __shared__ float sc[1216];
    int b = blockIdx.x, lane = threadIdx.x;  // 64 threads
    float qn = fmaxf(sqrtf(qss[b]), 1e-12f);
    int sq = seaq[b];
    float yqv = yq[b];
    for (int m = lane; m < 1216; m += 64) {
        float v = -3e38f;
        if (m < 1196) {
            float s = dotp[b*1196 + m] / (qn * fmaxf(sqrtf(mn2[m]), 1e-12f));
            if (seam[m] != sq) s = -10000.0f;
            float dy = fabsf(yqv - ym[m]);
            v = s * (1.0f - 0.5f * expf(-0.5f * dy));
        }
        sc[m] = v;
    }
    __syncthreads();
    for (int kk = 0; kk < 8; ++kk) {
        float bv = -3e38f; int bi = 0x7fffffff;
        for (int m = lane; m < 1216; m += 64) {
            float v = sc[m];
            if (v > bv) { bv = v; bi = m; }
        }
        #pragma unroll
        for (int mk = 1; mk < 64; mk <<= 1) {
            float ov = __shfl_xor(bv, mk, 64);
            int   oi = __shfl_xor(bi, mk, 64);
            if (ov > bv || (ov == bv && oi < bi)) { bv = ov; bi = oi; }
        }
        if (lane == 0) { idx[b*8 + kk] = bi; sc[bi] = -3e38f; }
        __syncthreads();
    }
}

// ---------------------------------------------------------------- merged q/k/v projection (grid 64+512+512)
__global__ __launch_bounds__(256) void qkv_kernel(const _Float16* __restrict__ qh,
                                                  const float* __restrict__ memb,
                                                  const int* __restrict__ idx,
                                                  const _Float16* __restrict__ wAll,
                                                  const float* __restrict__ ipb,
                                                  _Float16* __restrict__ qp,
                                                  _Float16* __restrict__ kp,
                                                  _Float16* __restrict__ vp)
{
    int bid = blockIdx.x;
    const _Float16* Wm; const float* bias; _Float16* Y; int blk; int kv;
    if (bid < 64)       { kv = 0; Wm = wAll;         bias = ipb;       Y = qp; blk = bid; }
    else if (bid < 576) { kv = 1; Wm = wAll + 16384; bias = ipb + 128; Y = kp; blk = bid - 64; }
    else                { kv = 1; Wm = wAll + 32768; bias = ipb + 256; Y = vp; blk = bid - 576; }

    int tid = threadIdx.x, w = tid >> 6, l = tid & 63, lr = l & 15, lk = l >> 4;
    int r0 = blk * 64 + w * 16;

    const float* Af = nullptr;
    const _Float16* Ah = nullptr;
    if (kv) {
        int bk = (blk * 64) >> 8;            // block-uniform
        int row = idx[bk];                   // retrieved memory row
        Af = memb + (size_t)row*32768 + ((r0 & 255) + lr)*128 + lk*8;
    } else {
        Ah = qh + (size_t)(r0 + lr)*128 + lk*8;
    }

    f32x4 acc[8];
    #pragma unroll
    for (int j = 0; j < 8; ++j) acc[j] = f32x4{0.f, 0.f, 0.f, 0.f};
    #pragma unroll
    for (int k0 = 0; k0 < 128; k0 += 32) {
        f16x8 a;
        if (kv) {
            float4 v0 = *(const float4*)&Af[k0];
            float4 v1 = *(const float4*)&Af[k0 + 4];
            a[0]=(_Float16)v0.x; a[1]=(_Float16)v0.y; a[2]=(_Float16)v0.z; a[3]=(_Float16)v0.w;
            a[4]=(_Float16)v1.x; a[5]=(_Float16)v1.y; a[6]=(_Float16)v1.z; a[7]=(_Float16)v1.w;
        } else {
            a = *(const f16x8*)&Ah[k0];
        }
        #pragma unroll
        for (int j = 0; j < 8; ++j) {
            f16x8 bb = *(const f16x8*)&Wm[(j*16 + lr)*128 + k0 + lk*8];
            acc[j] = __builtin_amdgcn_mfma_f32_16x16x32_f16(a, bb, acc[j], 0, 0, 0);
        }
    }
    #pragma unroll
    for (int j = 0; j < 8; ++j) {
        #pragma unroll
        for (int r = 0; r < 4; ++r) {
            int row = r0 + lk*4 + r, col = j*16 + lr;
            Y[(size_t)row*128 + col] = (_Float16)(acc[j][r] + bias[col]);
        }
    }
}

// ---------------------------------------------------------------- K8: 8-key attention + fused combined out-projection
__global__ void attn_kernel(const _Float16* __restrict__ qp, const _Float16* __restrict__ kp,
                            const _Float16* __restrict__ vp, const _Float16* __restrict__ Wc,
                            const float* __restrict__ bc, float* __restrict__ outp)
{
    __shared__ float ctxs[128];
    int bn = blockIdx.x;                 // b*256+n
    int b = bn >> 8, n = bn & 255;
    int tid = threadIdx.x;               // 128, d = tid, h = tid>>5
    float qv = (float)qp[(size_t)bn*128 + tid];
    float sc[8];
    #pragma unroll
    for (int k = 0; k < 8; ++k) {
        float p = qv * (float)kp[(((size_t)(b*8 + k)*256 + n)*128) + tid];
        #pragma unroll
        for (int m = 1; m < 32; m <<= 1) p += __shfl_xor(p, m, 64);
        sc[k] = p * 0.17677669529663687f;   // 1/sqrt(32)
    }
    float mx = sc[0];
    #pragma unroll
    for (int k = 1; k < 8; ++k) mx = fmaxf(mx, sc[k]);
    float den = 0.f;
    #pragma unroll
    for (int k = 0; k < 8; ++k) { sc[k] = expf(sc[k] - mx); den += sc[k]; }
    float inv = 1.f / den;
    float c = 0.f;
    #pragma unroll
    for (int k = 0; k < 8; ++k)
        c += sc[k] * (float)vp[(((size_t)(b*8 + k)*256 + n)*128) + tid];
    ctxs[tid] = c * inv;
    __syncthreads();

    // outp[bn][e=tid] = ctx . Wc[e][:] + bc[e]
    float s = bc[tid];
    const f16x8* wrow = (const f16x8*)&Wc[(size_t)tid*128];
    #pragma unroll
    for (int c0 = 0; c0 < 16; ++c0) {
        f16x8 wv = wrow[c0];
        #pragma unroll
        for (int u = 0; u < 8; ++u)
            s = fmaf(ctxs[c0*8 + u], (float)wv[u], s);
    }
    outp[(size_t)bn*128 + tid] = s;
}

// ================================================================ launch
extern "C" void kernel_launch(void* const* d_in, const int* in_sizes, int n_in,
                              void* d_out, int out_size, void* d_ws, size_t ws_size,
                              hipStream_t stream)
{
    const float* x_scalar = (const float*)d_in[0];
    const int*   season_q = (const int*)d_in[1];
    const float* year_q   = (const float*)d_in[2];
    const float* dw_w     = (const float*)d_in[3];
    const float* dw_b     = (const float*)d_in[4];
    const float* pw_w     = (const float*)d_in[5];
    const float* pw_b     = (const float*)d_in[6];
    const float* ln_g     = (const float*)d_in[7];
    const float* ln_b     = (const float*)d_in[8];
    const float* memb     = (const float*)d_in[9];
    const int*   mseas    = (const int*)d_in[10];
    const float* myear    = (const float*)d_in[11];
    const float* ipw      = (const float*)d_in[12];
    const float* ipb      = (const float*)d_in[13];
    const float* opw      = (const float*)d_in[14];
    const float* opb      = (const float*)d_in[15];
    const float* pjw      = (const float*)d_in[16];
    const float* pjb      = (const float*)d_in[17];

    char* wsb = (char*)d_ws;
    _Float16* Wf   = (_Float16*)(wsb + 0);            // 16,777,216
    _Float16* Gt   = (_Float16*)(wsb + 16777216);     //  1,048,576
    float*    qss  = (float*)   (wsb + 20971520);     //        64
    float*    dotp = (float*)   (wsb + 20971584);     //     76,544
    float*    mn2  = (float*)   (wsb + 21048128);     //      4,784
    int*      idxb = (int*)     (wsb + 21052928);     //        512
    _Float16* qp   = (_Float16*)(wsb + 29442048);     //  1,048,576
    _Float16* kp   = (_Float16*)(wsb + 30490624);     //  8,388,608
    _Float16* vp   = (_Float16*)(wsb + 38879232);     //  8,388,608
    _Float16* Wcf  = (_Float16*)(wsb + 48316416);     //     32,768
    float*    bc   = (float*)   (wsb + 48349184);     //        512
    _Float16* wAll = (_Float16*)(wsb + 49364992);     //    163,840
    _Float16* qlo  = (_Float16*)(wsb + 49528832);     //  1,048,576
    _Float16* qh   = (_Float16*)(wsb + 19922944);     //  1,048,576

    float* outp = (float*)d_out;
    float* qout = (float*)d_out + 524288;

    // merged: pw_w->f16 | small weights->f16 | zero accumulators | Wc=pjw@opw + bc
    cvt_pw_kernel<<<8596, 256, 0, stream>>>(pw_w, Wf, ipw, opw, pjw, opb, pjb, wAll,
                                            (float*)(wsb + 20971520), Wcf, bc);
    conv_kernel<<<dim3(16, 128), 256, 0, stream>>>(x_scalar, dw_w, dw_b, Gt);

    // big fused pointwise GEMM + gelu + mean + layernorm (writes qout/qh/qlo/qss)
    pw_kernel<<<4096, 256, 0, stream>>>(Wf, Gt, pw_b, ln_g, ln_b, qout, qh, qlo, qss);

    // similarity via MFMA + norms, then masked/diversity top-8
    simgemm_kernel<<<dim3(32, 75), 256, 0, stream>>>(qh, qlo, memb, dotp, mn2);
    topk_kernel<<<16, 64, 0, stream>>>(dotp, mn2, qss, season_q, year_q, mseas, myear, idxb);

    // merged q/k/v projections (K/V gather directly from memory_bank via idx)
    qkv_kernel<<<1088, 256, 0, stream>>>(qh, memb, idxb, wAll, ipb, qp, kp, vp);

    // attention + fused combined output projection (writes outp f32 directly)
    attn_kernel<<<4096, 128, 0, stream>>>(qp, kp, vp, Wcf, bc, outp);
}

// Round 15
// 198.706 us; speedup vs baseline: 1.5691x; 1.0246x over previous
//
#include <hip/hip_runtime.h>

typedef _Float16 f16x8 __attribute__((ext_vector_type(8)));
typedef _Float16 f16x4 __attribute__((ext_vector_type(4)));
typedef float    f32x4 __attribute__((ext_vector_type(4)));

// exact-erf GELU via Abramowitz-Stegun 7.1.26 (|erf err| <= 1.5e-7), ~14 VALU ops
__device__ __forceinline__ float gelu_f(float x) {
    float z  = 0.70710678118654752440f * x;
    float az = fabsf(z);
    float t  = 1.0f / fmaf(0.3275911f, az, 1.0f);
    float e  = __expf(-az * az);
    float p  = t * fmaf(t, fmaf(t, fmaf(t, fmaf(t, 1.061405429f, -1.453152027f),
                                        1.421413741f), -0.284496736f), 0.254829592f);
    float er = fmaf(-p, e, 1.0f);          // erf(|z|)
    float s  = (z < 0.0f) ? -er : er;      // erf(z), odd
    return 0.5f * x * (1.0f + s);
}

// async global->LDS, 16B per lane (dest = wave-uniform base + lane*16)
__device__ __forceinline__ void gload16(const void* g, void* l) {
    __builtin_amdgcn_global_load_lds(
        (const __attribute__((address_space(1))) unsigned int*)g,
        (__attribute__((address_space(3))) unsigned int*)l, 16, 0, 0);
}

// ---------------------------------------------------------------- K1: conv+gelu
__global__ void conv_kernel(const float* __restrict__ xs, const float* __restrict__ dww,
                            const float* __restrict__ dwb, _Float16* __restrict__ Gt)
{
    int b = blockIdx.x, t = blockIdx.y, n = threadIdx.x;
    float g = 0.f;
    if (t < 97) {
        float y = 0.f;
        #pragma unroll
        for (int j = 0; j < 12; ++j) {
            int tt = t + j - 6;
            if (tt >= 0 && tt < 96)
                y += dww[n*12 + j] * xs[((size_t)b*96 + tt)*256 + n];
        }
        g = gelu_f(y + dwb[n]);
    }
    Gt[((size_t)b*128 + t)*256 + n] = (_Float16)g;
}

// ---------------------------------------------------------------- K-cvt (merged: pw_w cvt | small-w cvt | zero | Wc=pjw@opw)
__global__ void cvt_pw_kernel(const float* __restrict__ src, _Float16* __restrict__ dst,
                              const float* __restrict__ ipw, const float* __restrict__ opw,
                              const float* __restrict__ pjw, const float* __restrict__ opb,
                              const float* __restrict__ pjb, _Float16* __restrict__ wAll,
                              float* __restrict__ zp, _Float16* __restrict__ Wcf,
                              float* __restrict__ bc)
{
    int bid = blockIdx.x, tid = threadIdx.x;
    if (bid < 8192) {
        size_t i = ((size_t)bid*256 + tid) * 4;
        float4 v = *(const float4*)&src[i];
        f16x4 o; o[0] = (_Float16)v.x; o[1] = (_Float16)v.y; o[2] = (_Float16)v.z; o[3] = (_Float16)v.w;
        *(f16x4*)&dst[i] = o;
    } else if (bid < 8512) {
        int i = (bid - 8192)*256 + tid;  // < 81920
        float v = (i < 49152) ? ipw[i] : (i < 65536 ? opw[i - 49152] : pjw[i - 65536]);
        wAll[i] = (_Float16)v;
    } else if (bid < 8532) {
        int i = (bid - 8512)*256 + tid;  // zero 20348 floats = 5087 float4
        if (i < 5087) {
            float4 z = {0.f, 0.f, 0.f, 0.f};
            *(float4*)&zp[i*4] = z;
        }
    } else {
        // Wc[e][c] = sum_d pjw[e][d] * opw[d][c]  (combined out-projection), f16
        int e = (bid - 8532)*2 + (tid >> 7);
        int c = tid & 127;
        float acc = 0.f;
        for (int d = 0; d < 128; ++d)
            acc = fmaf(pjw[e*128 + d], opw[d*128 + c], acc);
        Wcf[e*128 + c] = (_Float16)acc;
        if (c == 0) {
            float s = pjb[e];
            for (int d = 0; d < 128; ++d)
                s = fmaf(pjw[e*128 + d], opb[d], s);
            bc[e] = s;
        }
    }
}

// ---------------------------------------------------------------- K2: pointwise GEMM + gelu + mean + LAYERNORM
// R14 structure. New: LN epilogue ALSO writes qhT/qloT in MFMA-fragment-major
// layout (chunk32-major: [chunk][row=b][lk][8]) so sim's q loads are contiguous.
__global__ __launch_bounds__(256) void pw_kernel(const _Float16* __restrict__ W,
                                                 const _Float16* __restrict__ Gt,
                                                 const float* __restrict__ pwb,
                                                 const float* __restrict__ lng,
                                                 const float* __restrict__ lnb,
                                                 float* __restrict__ qout,
                                                 _Float16* __restrict__ qh,
                                                 _Float16* __restrict__ qhT,
                                                 _Float16* __restrict__ qloT,
                                                 float* __restrict__ qss)
{
    __shared__ __align__(16) _Float16 As[2][128][32];  // 16KB
    __shared__ __align__(16) _Float16 Bs[2][128][32];  // 16KB

    int x = blockIdx.x;
    int xcd = x & 7, ii = x >> 3;
    int ob = xcd * 32 + (ii >> 4);   // o-block = n (slow)
    int b  = ii & 15;                // batch (fast, A-tile L2 reuse)
    const _Float16* Arow = W  + (size_t)ob * 128 * 256;
    const _Float16* Brow = Gt + (size_t)b  * 128 * 256;

    int tid = threadIdx.x, w = tid >> 6, l = tid & 63, lr = l & 15, lk = l >> 4;
    int wr = w >> 1, wc = w & 1;
    int rsw = (lr >> 1) & 3;                 // read-slot XOR key

    f32x4 acc[4][4];
    #pragma unroll
    for (int i = 0; i < 4; ++i)
        #pragma unroll
        for (int j = 0; j < 4; ++j)
            acc[i][j] = f32x4{0.f, 0.f, 0.f, 0.f};

    auto stage = [&](int buf, int k0) {
        #pragma unroll
        for (int j = 0; j < 2; ++j) {
            int chunk = tid + j*256;          // 0..511; LDS dest = chunk*16B (linear)
            int row = chunk >> 2;
            int co  = (chunk & 3) * 8;                        // dest col (halves)
            int cos = ((chunk & 3) ^ ((chunk >> 3) & 3)) * 8; // swizzled source col
            gload16(&Arow[row*256 + k0 + cos], &As[buf][row][co]);
            gload16(&Brow[row*256 + k0 + cos], &Bs[buf][row][co]);
        }
    };

    stage(0, 0);
    __syncthreads();
    for (int ks = 0; ks < 8; ++ks) {
        int cur = ks & 1;
        if (ks < 7) stage(cur ^ 1, (ks + 1) * 32);
        f16x8 a[4], bb[4];
        #pragma unroll
        for (int i = 0; i < 4; ++i)
            a[i]  = *(const f16x8*)&As[cur][wr*64 + i*16 + lr][(lk ^ rsw)*8];
        #pragma unroll
        for (int j = 0; j < 4; ++j)
            if (wc == 0 || j < 3)            // wc=1, j=3 -> t=112..127 all padding
                bb[j] = *(const f16x8*)&Bs[cur][wc*64 + j*16 + lr][(lk ^ rsw)*8];
        #pragma unroll
        for (int i = 0; i < 4; ++i)
            #pragma unroll
            for (int j = 0; j < 4; ++j)
                if (wc == 0 || j < 3)
                    acc[i][j] = __builtin_amdgcn_mfma_f32_16x16x32_f16(bb[j], a[i], acc[i][j], 0, 0, 0);
        __syncthreads();
    }

    // epilogue: per lane o = wr*64+i*16+lr; t-values live in (j, lk, r)
    float (*red)[2] = reinterpret_cast<float(*)[2]>(&As[0][0][0]);
    #pragma unroll
    for (int i = 0; i < 4; ++i) {
        int og = ob*128 + wr*64 + i*16 + lr;
        float pbv = pwb[og];
        float s = 0.f;
        if (wc == 0) {
            #pragma unroll
            for (int j = 0; j < 4; ++j)
                #pragma unroll
                for (int r = 0; r < 4; ++r)
                    s += gelu_f(acc[i][j][r] + pbv);      // t = j*16+lk*4+r <= 63
        } else {
            #pragma unroll
            for (int j = 0; j < 2; ++j)
                #pragma unroll
                for (int r = 0; r < 4; ++r)
                    s += gelu_f(acc[i][j][r] + pbv);      // t = 64..95
            if (lk == 0) s += gelu_f(acc[i][2][0] + pbv); // t = 96 only
        }
        s += __shfl_xor(s, 16, 64);
        s += __shfl_xor(s, 32, 64);
        if (lk == 0) red[wr*64 + i*16 + lr][wc] = s;
    }
    __syncthreads();

    // fused layernorm over the block's 128 o-values (= LN row (b, n=ob)); wave 0 only
    if (w == 0) {
        float x0 = (red[l][0]      + red[l][1])      * (1.f/97.f);
        float x1 = (red[64 + l][0] + red[64 + l][1]) * (1.f/97.f);
        float sm = x0 + x1;
        #pragma unroll
        for (int m = 1; m < 64; m <<= 1) sm += __shfl_xor(sm, m, 64);
        float mu = sm * (1.f/128.f);
        float d0 = x0 - mu, d1 = x1 - mu;
        float vv = d0*d0 + d1*d1;
        #pragma unroll
        for (int m = 1; m < 64; m <<= 1) vv += __shfl_xor(vv, m, 64);
        float rs = 1.0f / sqrtf(vv * (1.f/128.f) + 1e-5f);
        float q0 = d0*rs*lng[l]      + lnb[l];
        float q1 = d1*rs*lng[64 + l] + lnb[64 + l];
        size_t bn = (size_t)b*256 + ob;
        qout[bn*128 + l]      = q0;
        qout[bn*128 + 64 + l] = q1;
        _Float16 h0 = (_Float16)q0, h1 = (_Float16)q1;
        qh[bn*128 + l]       = h0;
        qh[bn*128 + 64 + l]  = h1;
        // fragment-major layout for sim: chunk = (n*128+d)>>5; off = b*32+((d>>3)&3)*8+(d&7)
        int ch0 = ob*4 + (l >> 5);
        int sub = b*32 + ((l >> 3) & 3)*8 + (l & 7);
        qhT [ch0*512 + sub]       = h0;
        qhT [(ch0 + 2)*512 + sub] = h1;
        qloT[ch0*512 + sub]       = (_Float16)(q0 - (float)h0);
        qloT[(ch0 + 2)*512 + sub] = (_Float16)(q1 - (float)h1);
        float ss = q0*q0 + q1*q1;
        #pragma unroll
        for (int m = 1; m < 64; m <<= 1) ss += __shfl_xor(ss, m, 64);
        if (l == 0) atomicAdd(&qss[b], ss);
    }
}

// ---------------------------------------------------------------- K4: similarity via MFMA, LDS-staged mem
// q now read from fragment-major qhT/qloT: each wave-load is a lane-permuted
// CONTIGUOUS 1KB (was 16 cache lines at 64KB stride) -> 4x fewer transactions.
__global__ __launch_bounds__(256) void simgemm_kernel(const _Float16* __restrict__ qhT,
                                                      const _Float16* __restrict__ qloT,
                                                      const float* __restrict__ mem,
                                                      float* __restrict__ dotp,
                                                      float* __restrict__ mn2)
{
    __shared__ __align__(16) float Ms[2][16][256];   // 16KB per buf
    __shared__ f32x4 redls[4][64];
    __shared__ float redn[4][16];

    int tid = threadIdx.x, w = tid >> 6, l = tid & 63, lr = l & 15, lk = l >> 4;
    int m0 = blockIdx.y * 16;
    int kwin = blockIdx.x * 1024;
    int rowm = m0 + lr;

    auto stage = [&](int buf, int sw) {
        #pragma unroll
        for (int j = 0; j < 4; ++j) {
            int r = w*4 + j;                          // local row, wave-uniform
            int rowg = m0 + r; if (rowg > 1195) rowg = 1195;
            const float* src = mem + (size_t)rowg*32768 + kwin + sw*256 + (l ^ (r & 7))*4;
            gload16(src, &Ms[buf][r][0]);             // + lane*16B by HW
        }
    };

    f32x4 acc_a = {0.f,0.f,0.f,0.f}, acc_b = {0.f,0.f,0.f,0.f};
    float nacc = 0.f;

    stage(0, 0);
    __syncthreads();
    for (int sw = 0; sw < 4; ++sw) {
        int cur = sw & 1;
        if (sw < 3) stage(cur ^ 1, sw + 1);
        #pragma unroll
        for (int cc = 0; cc < 2; ++cc) {
            int kl = w*64 + cc*32;                    // k within sub-window
            int s0 = (kl + lk*8) >> 2;                // 16B slot 0..62
            float4 v0 = *(const float4*)&Ms[cur][lr][(s0       ^ (lr & 7))*4];
            float4 v1 = *(const float4*)&Ms[cur][lr][((s0 + 1) ^ (lr & 7))*4];
            int chunk = (kwin + sw*256 + kl) >> 5;    // wave-uniform
            int fo = lr*4 + lk;                       // lane slot within 1KB chunk
            f16x8 ah = ((const f16x8*)(qhT  + (size_t)chunk*512))[fo];
            f16x8 al = ((const f16x8*)(qloT + (size_t)chunk*512))[fo];
            float e0 = v0.x, e1 = v0.y, e2 = v0.z, e3 = v0.w;
            float e4 = v1.x, e5 = v1.y, e6 = v1.z, e7 = v1.w;
            f16x8 bh;
            bh[0]=(_Float16)e0; bh[1]=(_Float16)e1; bh[2]=(_Float16)e2; bh[3]=(_Float16)e3;
            bh[4]=(_Float16)e4; bh[5]=(_Float16)e5; bh[6]=(_Float16)e6; bh[7]=(_Float16)e7;
            nacc = fmaf(e0,e0, fmaf(e1,e1, fmaf(e2,e2, fmaf(e3,e3, nacc))));
            nacc = fmaf(e4,e4, fmaf(e5,e5, fmaf(e6,e6, fmaf(e7,e7, nacc))));
            acc_a = __builtin_amdgcn_mfma_f32_16x16x32_f16(ah, bh, acc_a, 0, 0, 0);
            acc_b = __builtin_amdgcn_mfma_f32_16x16x32_f16(al, bh, acc_b, 0, 0, 0);
        }
        __syncthreads();
    }

    // mem row norms within wave (lanes lr,lr+16,lr+32,lr+48 share a row)
    nacc += __shfl_xor(nacc, 16, 64);
    nacc += __shfl_xor(nacc, 32, 64);

    // cross-wave reduction, one atomic set per block
    f32x4 tot = acc_a + acc_b;
    redls[w][l] = tot;
    if (lk == 0) redn[w][lr] = nacc;
    __syncthreads();
    if (w == 0) {
        tot = redls[0][l];
        tot += redls[1][l]; tot += redls[2][l]; tot += redls[3][l];
        if (rowm < 1196) {
            #pragma unroll
            for (int r = 0; r < 4; ++r)
                atomicAdd(&dotp[(lk*4 + r)*1196 + rowm], tot[r]);
            if (lk == 0)
                atomicAdd(&mn2[rowm], redn[0][lr] + redn[1][lr] + redn[2][lr] + redn[3][lr]);
        }
    }
}

// ---------------------------------------------------------------- K5: finalize sim + top-8
__global__ void topk_kernel(const float* __restrict__ dotp, const float* __restrict__ mn2,
                            const float* __restrict__ qss, const int* __restrict__ seaq,
                            const float* __restrict__ yq, const int* __restrict__ seam,
                            const float* __restrict__ ym, int* __restrict__ idx)
{
    __shared__ float sc[1216];
    int b = blockIdx.x, lane = threadIdx.x;  // 64 threads
    float qn = fmaxf(sqrtf(qss[b]), 1e-12f);
    int sq = seaq[b];
    float yqv = yq[b];
    for (int m = lane; m < 1216; m += 64) {
        float v = -3e38f;
        if (m < 1196) {
            float s = dotp[b*1196 + m] / (qn * fmaxf(sqrtf(mn2[m]), 1e-12f));
            if (seam[m] != sq) s = -10000.0f;
            float dy = fabsf(yqv - ym[m]);
            v = s * (1.0f - 0.5f * expf(-0.5f * dy));
        }
        sc[m] = v;
    }
    __syncthreads();
    for (int kk = 0; kk < 8; ++kk) {
        float bv = -3e38f; int bi = 0x7fffffff;
        for (int m = lane; m < 1216; m += 64) {
            float v = sc[m];
            if (v > bv) { bv = v; bi = m; }
        }
        #pragma unroll
        for (int mk = 1; mk < 64; mk <<= 1) {
            float ov = __shfl_xor(bv, mk, 64);
            int   oi = __shfl_xor(bi, mk, 64);
            if (ov > bv || (ov == bv && oi < bi)) { bv = ov; bi = oi; }
        }
        if (lane == 0) { idx[b*8 + kk] = bi; sc[bi] = -3e38f; }
        __syncthreads();
    }
}

// ---------------------------------------------------------------- merged q + fused K/V projections (grid 64+512)
// KV block loads/converts each memory fragment ONCE and feeds both Wk and Wv.
__global__ __launch_bounds__(256) void qkv_kernel(const _Float16* __restrict__ qh,
                                                  const float* __restrict__ memb,
                                                  const int* __restrict__ idx,
                                                  const _Float16* __restrict__ wAll,
                                                  const float* __restrict__ ipb,
                                                  _Float16* __restrict__ qp,
                                                  _Float16* __restrict__ kp,
                                                  _Float16* __restrict__ vp)
{
    int bid = blockIdx.x;
    int tid = threadIdx.x, w = tid >> 6, l = tid & 63, lr = l & 15, lk = l >> 4;

    if (bid < 64) {
        // q projection (unchanged)
        int r0 = bid * 64 + w * 16;
        const _Float16* Ah = qh + (size_t)(r0 + lr)*128 + lk*8;
        f32x4 acc[8];
        #pragma unroll
        for (int j = 0; j < 8; ++j) acc[j] = f32x4{0.f, 0.f, 0.f, 0.f};
        #pragma unroll
        for (int k0 = 0; k0 < 128; k0 += 32) {
            f16x8 a = *(const f16x8*)&Ah[k0];
            #pragma unroll
            for (int j = 0; j < 8; ++j) {
                f16x8 bb = *(const f16x8*)&wAll[(j*16 + lr)*128 + k0 + lk*8];
                acc[j] = __builtin_amdgcn_mfma_f32_16x16x32_f16(a, bb, acc[j], 0, 0, 0);
            }
        }
        #pragma unroll
        for (int j = 0; j < 8; ++j) {
            #pragma unroll
            for (int r = 0; r < 4; ++r) {
                int row = r0 + lk*4 + r, col = j*16 + lr;
                qp[(size_t)row*128 + col] = (_Float16)(acc[j][r] + ipb[col]);
            }
        }
    } else {
        int blk = bid - 64;                  // 0..511
        int r0 = blk * 64 + w * 16;
        int bk = (blk * 64) >> 8;            // block-uniform
        int row = idx[bk];
        const float* Af = memb + (size_t)row*32768 + ((r0 & 255) + lr)*128 + lk*8;
        const _Float16* Wk = wAll + 16384;
        const _Float16* Wv = wAll + 32768;

        f32x4 acck[8], accv[8];
        #pragma unroll
        for (int j = 0; j < 8; ++j) { acck[j] = f32x4{0.f,0.f,0.f,0.f}; accv[j] = f32x4{0.f,0.f,0.f,0.f}; }
        #pragma unroll
        for (int k0 = 0; k0 < 128; k0 += 32) {
            float4 v0 = *(const float4*)&Af[k0];
            float4 v1 = *(const float4*)&Af[k0 + 4];
            f16x8 a;
            a[0]=(_Float16)v0.x; a[1]=(_Float16)v0.y; a[2]=(_Float16)v0.z; a[3]=(_Float16)v0.w;
            a[4]=(_Float16)v1.x; a[5]=(_Float16)v1.y; a[6]=(_Float16)v1.z; a[7]=(_Float16)v1.w;
            #pragma unroll
            for (int j = 0; j < 8; ++j) {
                f16x8 bk_ = *(const f16x8*)&Wk[(j*16 + lr)*128 + k0 + lk*8];
                acck[j] = __builtin_amdgcn_mfma_f32_16x16x32_f16(a, bk_, acck[j], 0, 0, 0);
                f16x8 bv_ = *(const f16x8*)&Wv[(j*16 + lr)*128 + k0 + lk*8];
                accv[j] = __builtin_amdgcn_mfma_f32_16x16x32_f16(a, bv_, accv[j], 0, 0, 0);
            }
        }
        #pragma unroll
        for (int j = 0; j < 8; ++j) {
            #pragma unroll
            for (int r = 0; r < 4; ++r) {
                int row2 = r0 + lk*4 + r, col = j*16 + lr;
                kp[(size_t)row2*128 + col] = (_Float16)(acck[j][r] + ipb[128 + col]);
                vp[(size_t)row2*128 + col] = (_Float16)(accv[j][r] + ipb[256 + col]);
            }
        }
    }
}

// ---------------------------------------------------------------- K8: 8-key attention + fused combined out-projection
__global__ void attn_kernel(const _Float16* __restrict__ qp, const _Float16* __restrict__ kp,
                            const _Float16* __restrict__ vp, const _Float16* __restrict__ Wc,
                            const float* __restrict__ bc, float* __restrict__ outp)
{
    __shared__ float ctxs[128];
    int bn = blockIdx.x;                 // b*256+n
    int b = bn >> 8, n = bn & 255;
    int tid = threadIdx.x;               // 128, d = tid, h = tid>>5
    float qv = (float)qp[(size_t)bn*128 + tid];
    float sc[8];
    #pragma unroll
    for (int k = 0; k < 8; ++k) {
        float p = qv * (float)kp[(((size_t)(b*8 + k)*256 + n)*128) + tid];
        #pragma unroll
        for (int m = 1; m < 32; m <<= 1) p += __shfl_xor(p, m, 64);
        sc[k] = p * 0.17677669529663687f;   // 1/sqrt(32)
    }
    float mx = sc[0];
    #pragma unroll
    for (int k = 1; k < 8; ++k) mx = fmaxf(mx, sc[k]);
    float den = 0.f;
    #pragma unroll
    for (int k = 0; k < 8; ++k) { sc[k] = expf(sc[k] - mx); den += sc[k]; }
    float inv = 1.f / den;
    float c = 0.f;
    #pragma unroll
    for (int k = 0; k < 8; ++k)
        c += sc[k] * (float)vp[(((size_t)(b*8 + k)*256 + n)*128) + tid];
    ctxs[tid] = c * inv;
    __syncthreads();

    // outp[bn][e=tid] = ctx . Wc[e][:] + bc[e]
    float s = bc[tid];
    const f16x8* wrow = (const f16x8*)&Wc[(size_t)tid*128];
    #pragma unroll
    for (int c0 = 0; c0 < 16; ++c0) {
        f16x8 wv = wrow[c0];
        #pragma unroll
        for (int u = 0; u < 8; ++u)
            s = fmaf(ctxs[c0*8 + u], (float)wv[u], s);
    }
    outp[(size_t)bn*128 + tid] = s;
}

// ================================================================ launch
extern "C" void kernel_launch(void* const* d_in, const int* in_sizes, int n_in,
                              void* d_out, int out_size, void* d_ws, size_t ws_size,
                              hipStream_t stream)
{
    const float* x_scalar = (const float*)d_in[0];
    const int*   season_q = (const int*)d_in[1];
    const float* year_q   = (const float*)d_in[2];
    const float* dw_w     = (const float*)d_in[3];
    const float* dw_b     = (const float*)d_in[4];
    const float* pw_w     = (const float*)d_in[5];
    const float* pw_b     = (const float*)d_in[6];
    const float* ln_g     = (const float*)d_in[7];
    const float* ln_b     = (const float*)d_in[8];
    const float* memb     = (const float*)d_in[9];
    const int*   mseas    = (const int*)d_in[10];
    const float* myear    = (const float*)d_in[11];
    const float* ipw      = (const float*)d_in[12];
    const float* ipb      = (const float*)d_in[13];
    const float* opw      = (const float*)d_in[14];
    const float* opb      = (const float*)d_in[15];
    const float* pjw      = (const float*)d_in[16];
    const float* pjb      = (const float*)d_in[17];

    char* wsb = (char*)d_ws;
    _Float16* Wf   = (_Float16*)(wsb + 0);            // 16,777,216
    _Float16* Gt   = (_Float16*)(wsb + 16777216);     //  1,048,576
    _Float16* qloT = (_Float16*)(wsb + 17825792);     //  1,048,576 (old xmean slot)
    _Float16* qh   = (_Float16*)(wsb + 19922944);     //  1,048,576 (row-major, for qkv)
    float*    qss  = (float*)   (wsb + 20971520);     //        64
    float*    dotp = (float*)   (wsb + 20971584);     //     76,544
    float*    mn2  = (float*)   (wsb + 21048128);     //      4,784
    int*      idxb = (int*)     (wsb + 21052928);     //        512
    _Float16* qp   = (_Float16*)(wsb + 29442048);     //  1,048,576
    _Float16* kp   = (_Float16*)(wsb + 30490624);     //  8,388,608
    _Float16* vp   = (_Float16*)(wsb + 38879232);     //  8,388,608
    _Float16* Wcf  = (_Float16*)(wsb + 48316416);     //     32,768
    float*    bc   = (float*)   (wsb + 48349184);     //        512
    _Float16* wAll = (_Float16*)(wsb + 49364992);     //    163,840
    _Float16* qhT  = (_Float16*)(wsb + 49528832);     //  1,048,576 (fragment-major)

    float* outp = (float*)d_out;
    float* qout = (float*)d_out + 524288;

    // merged: pw_w->f16 | small weights->f16 | zero accumulators | Wc=pjw@opw + bc
    cvt_pw_kernel<<<8596, 256, 0, stream>>>(pw_w, Wf, ipw, opw, pjw, opb, pjb, wAll,
                                            (float*)(wsb + 20971520), Wcf, bc);
    conv_kernel<<<dim3(16, 128), 256, 0, stream>>>(x_scalar, dw_w, dw_b, Gt);

    // big fused pointwise GEMM + gelu + mean + layernorm (writes qout/qh/qhT/qloT/qss)
    pw_kernel<<<4096, 256, 0, stream>>>(Wf, Gt, pw_b, ln_g, ln_b, qout, qh, qhT, qloT, qss);

    // similarity via MFMA (fragment-major q) + norms, then masked/diversity top-8
    simgemm_kernel<<<dim3(32, 75), 256, 0, stream>>>(qhT, qloT, memb, dotp, mn2);
    topk_kernel<<<16, 64, 0, stream>>>(dotp, mn2, qss, season_q, year_q, mseas, myear, idxb);

    // q + fused K/V projections (memory fragments loaded once, fed to Wk and Wv)
    qkv_kernel<<<576, 256, 0, stream>>>(qh, memb, idxb, wAll, ipb, qp, kp, vp);

    // attention + fused combined output projection (writes outp f32 directly)
    attn_kernel<<<4096, 128, 0, stream>>>(qp, kp, vp, Wcf, bc, outp);
}